// Round 9
// baseline (1214.643 us; speedup 1.0000x reference)
//
#include <hip/hip_runtime.h>
#include <cstddef>
#include <cstdint>

// MinimalRNNCell h_T: purely linear scan.
//   g_c = sum_{i<8} x_{8c+i} @ (W R^{7-i}) -- ONE MFMA GEMM (x-gather @ stacked G^T)
//   8-level tree combine with Q_l = R^(8*2^l); h0 injected into chunk 0 pre-tree.
// R9:
//  - mk v2: BK=32, pair-packed 128B LDS lines (conflict-free both sides), dbuf
//    64 KB -> 2 blocks/CU. Fixes the ~60us/launch tail (12 launches).
//  - main5: A reg-staged directly from f32 x (split_x pass deleted); extended
//    row swizzle (r&7)^(((r>>3)&3)<<1) keeps A ds_writes conflict-free.
//  - numerics unchanged from R8 (x->f16 one-shot; G/R-chain 2-term split;
//    scale-managed R^512/R^1024; fp32 accumulate). Same summation order.

namespace {

constexpr int BATCH = 32;
constexpr int T = 2048;
constexpr int U = 1024;
constexpr int LJ = 8;
constexpr int CJ = T / LJ;      // 256 chunks
constexpr int MJ = CJ * BATCH;  // 8192 aggregate rows

typedef _Float16 f16;
typedef _Float16 f16x4 __attribute__((ext_vector_type(4)));
typedef _Float16 f16x8 __attribute__((ext_vector_type(8)));
typedef float f32x4 __attribute__((ext_vector_type(4)));

__device__ inline void gload16(const void* g, void* l) {
    __builtin_amdgcn_global_load_lds(
        (const __attribute__((address_space(1))) unsigned int*)g,
        (__attribute__((address_space(3))) unsigned int*)l, 16, 0, 0);
}

// ---------------- transpose + split fp32 [1024][1024] -> T-split --------------
__global__ __launch_bounds__(256)
void tsplit(const float* __restrict__ S, f16* __restrict__ Dh, f16* __restrict__ Dl,
            long dstride, long doff)
{
    __shared__ float tile[32][33];
    const int t = threadIdx.x;
    const int k0 = blockIdx.x * 32;
    const int n0 = blockIdx.y * 32;
    {
        const int r = t >> 3, c4 = (t & 7) << 2;
        const float4 v = *(const float4*)(S + (size_t)(k0 + r) * U + n0 + c4);
        tile[r][c4 + 0] = v.x; tile[r][c4 + 1] = v.y;
        tile[r][c4 + 2] = v.z; tile[r][c4 + 3] = v.w;
    }
    __syncthreads();
    {
        const int c = t >> 3, r4 = (t & 7) << 2;
        float v0 = tile[r4 + 0][c], v1 = tile[r4 + 1][c],
              v2 = tile[r4 + 2][c], v3 = tile[r4 + 3][c];
        f16x4 h, lo;
        h.x = (f16)v0; lo.x = (f16)((v0 - (float)h.x) * 2048.0f);
        h.y = (f16)v1; lo.y = (f16)((v1 - (float)h.y) * 2048.0f);
        h.z = (f16)v2; lo.z = (f16)((v2 - (float)h.z) * 2048.0f);
        h.w = (f16)v3; lo.w = (f16)((v3 - (float)h.w) * 2048.0f);
        const size_t o = (size_t)(n0 + c) * dstride + doff + k0 + r4;
        *(f16x4*)(Dh + o) = h;
        *(f16x4*)(Dl + o) = lo;
    }
}

// ---------------- main GEMM: g0[8192][1024] = f16(x)-gather @ (Gh + 2^-11 Gl) ----
// 256x128 tile, 512 thr (8 waves 4x2), BK=64, dual acc, dbuf LDS, A reg-staged
// from f32 x (in-kernel f16 convert; no xh buffer, no split_x pass).
__global__ __launch_bounds__(512, 2)
void main5(const float* __restrict__ x, const f16* __restrict__ GhT,
           const f16* __restrict__ GlT, float* __restrict__ g0)
{
    __shared__ __align__(16) f16 LA[2][16384];   // 32 KB / buf (h only)
    __shared__ __align__(16) f16 LBh[2][8192];   // 16 KB / buf
    __shared__ __align__(16) f16 LBl[2][8192];   // 16 KB / buf

    const int tid  = threadIdx.x;        // 0..511
    const int lane = tid & 63;
    const int w    = tid >> 6;           // 0..7
    const int wm   = w >> 1;             // 0..3 row quarter (64 rows)
    const int wn   = w & 1;              // 0..1 col half (64 cols)
    const int r0   = blockIdx.x * 256;   // 32 row tiles; bid%8 = rowtile%8 -> XCD
    const int c0   = blockIdx.y * 128;   // 8 col blocks

    // ---- A staging (reg): row = tid>>1, half = tid&1 covers 32 floats
    const int arr   = tid >> 1;          // 0..255
    const int ahalf = tid & 1;
    const int arow  = r0 + arr;
    const float* aP = x + ((size_t)(arow & 31) * T + (size_t)(arow >> 5) * LJ) * U
                        + ahalf * 32;
    // extended swizzle S(r) = (r&7) ^ (((r>>3)&3)<<1): rows r,r+8,r+16,r+24 get
    // distinct slots -> conflict-free 16B ds_writes.
    const int aswz = (arr & 7) ^ (((arr >> 3) & 3) << 1);
    int awb[4];
    #pragma unroll
    for (int j = 0; j < 4; ++j)
        awb[j] = arr * 128 + (((ahalf * 4 + j) ^ aswz) << 4);

    // ---- B staging via gload16 (linear dest, pre-swizzled source)
    const int bch = tid & 7, rid = tid >> 3;   // 16B chunk, col-within-half
    size_t bof[2];
    #pragma unroll
    for (int q = 0; q < 2; ++q) {
        const int c = q * 64 + rid;      // tile col 0..127
        bof[q] = ((size_t)(c0 + c) << 14) + (size_t)((bch ^ (c & 7)) << 4);
    }
    const int dst = tid << 4;            // 0..8191 bytes

    f32x4 hh[4][4], xx[4][4];
    #pragma unroll
    for (int mi = 0; mi < 4; ++mi)
        #pragma unroll
        for (int ni = 0; ni < 4; ++ni) {
            hh[mi][ni] = (f32x4){0.f, 0.f, 0.f, 0.f};
            xx[mi][ni] = (f32x4){0.f, 0.f, 0.f, 0.f};
        }

    float4 areg[8];
    auto aload = [&](int kt) {
        const float* ap = aP + (size_t)kt * 64;
        #pragma unroll
        for (int i = 0; i < 8; ++i) areg[i] = *(const float4*)(ap + i * 4);
    };
    auto awrite = [&](int b) {
        #pragma unroll
        for (int j = 0; j < 4; ++j) {
            f16x8 h8;
            #pragma unroll
            for (int e = 0; e < 2; ++e) {
                const float4 v = areg[j * 2 + e];
                h8[e * 4 + 0] = (f16)v.x; h8[e * 4 + 1] = (f16)v.y;
                h8[e * 4 + 2] = (f16)v.z; h8[e * 4 + 3] = (f16)v.w;
            }
            *(f16x8*)((char*)&LA[b][0] + awb[j]) = h8;
        }
    };
    auto bload = [&](int b, int kt) {
        const size_t kb = (size_t)kt << 7;   // 64 f16 = 128 B
        #pragma unroll
        for (int q = 0; q < 2; ++q) {
            gload16((const char*)GhT + bof[q] + kb, (char*)&LBh[b][0] + q * 8192 + dst);
            gload16((const char*)GlT + bof[q] + kb, (char*)&LBl[b][0] + q * 8192 + dst);
        }
    };

    aload(0); bload(0, 0); awrite(0);
    __syncthreads();

    int buf = 0;
    #pragma unroll 1
    for (int kt = 0; kt < 128; ++kt) {
        const bool more = (kt + 1 < 128);
        if (more) { aload(kt + 1); bload(buf ^ 1, kt + 1); }

        #pragma unroll
        for (int ks = 0; ks < 2; ++ks) {
            const int kg = ks * 4 + (lane >> 4);
            f16x8 af[4], bh[4], bl[4];
            #pragma unroll
            for (int mi = 0; mi < 4; ++mi) {
                const int rr = wm * 64 + mi * 16 + (lane & 15);
                const int rs = (rr & 7) ^ (((rr >> 3) & 3) << 1);
                const int byte = rr * 128 + ((kg ^ rs) << 4);
                af[mi] = *(const f16x8*)((const char*)&LA[buf][0] + byte);
            }
            #pragma unroll
            for (int ni = 0; ni < 4; ++ni) {
                const int cc = wn * 64 + ni * 16 + (lane & 15);
                const int byte = cc * 128 + ((kg ^ (cc & 7)) << 4);
                bh[ni] = *(const f16x8*)((const char*)&LBh[buf][0] + byte);
                bl[ni] = *(const f16x8*)((const char*)&LBl[buf][0] + byte);
            }
            #pragma unroll
            for (int mi = 0; mi < 4; ++mi)
                #pragma unroll
                for (int ni = 0; ni < 4; ++ni) {
                    hh[mi][ni] = __builtin_amdgcn_mfma_f32_16x16x32_f16(af[mi], bh[ni], hh[mi][ni], 0, 0, 0);
                    xx[mi][ni] = __builtin_amdgcn_mfma_f32_16x16x32_f16(af[mi], bl[ni], xx[mi][ni], 0, 0, 0);
                }
        }

        if (more) awrite(buf ^ 1);
        __syncthreads();
        buf ^= 1;
    }

    // epilogue: C/D layout col=lane&15, row=(lane>>4)*4+reg (m89-verified)
    #pragma unroll
    for (int mi = 0; mi < 4; ++mi)
        #pragma unroll
        for (int ni = 0; ni < 4; ++ni) {
            const int col = c0 + wn * 64 + ni * 16 + (lane & 15);
            #pragma unroll
            for (int r = 0; r < 4; ++r) {
                const int row = r0 + wm * 64 + mi * 16 + ((lane >> 4) << 2) + r;
                g0[(size_t)row * U + col] = hh[mi][ni][r] + xx[mi][ni][r] * (1.0f / 2048.0f);
            }
        }
}

// ---------------- unified MFMA split-GEMM v2 (chain / squarings / combines) -----
// 128x128 tile, BK=32, pair-packed 128B LDS lines, dbuf 64 KB -> 2 blocks/CU.
struct MDesc {
    const float* A;
    const f16* BhT; const f16* BlT;
    float* C;
    f16* EhT; f16* ElT;
    long bstride, estride, eoff;
    int M, K;
    int amode;      // 0: row-major stride K   2: tree gather (+A2 add in epilogue)
    int cmode;      // 0: store  1: add
    float ascale, cscale, escale;
};

__global__ __launch_bounds__(256, 2)
void mk(MDesc d0, MDesc d1)
{
    MDesc d = blockIdx.z ? d1 : d0;
    const int r0 = blockIdx.y * 128;
    if (r0 >= d.M) return;
    const int c0 = blockIdx.x * 128;

    // pair-packed: line = 2 rows(cols) x 32k = 128 B; chunk ch = 4*(r&1)+kc
    __shared__ __align__(16) f16 LAs[2][2][4096];   // [buf][h/l] 8 KB each
    __shared__ __align__(16) f16 LBs[2][2][4096];

    const int tid = threadIdx.x;
    const int lane = tid & 63;
    const int w = tid >> 6;
    const int wm = w >> 1, wn = w & 1;

    // ---- A staging: row = tid>>1 (0..127), half = tid&1 (16 floats)
    const int arr = tid >> 1;
    const int ahalf = tid & 1;
    int arow = r0 + arr;
    if (arow >= d.M) arow = d.M - 1;
    const float* aP;
    if (d.amode == 2)
        aP = d.A + ((size_t)(((arow >> 5) << 6) + (arow & 31)) << 10);
    else
        aP = d.A + (size_t)arow * d.K;
    aP += ahalf * 16;
    int awb[2];
    #pragma unroll
    for (int j = 0; j < 2; ++j) {
        const int prow = arr >> 1;
        const int ch = 4 * (arr & 1) + 2 * ahalf + j;
        awb[j] = prow * 128 + ((ch ^ (prow & 7)) << 4);
    }

    // ---- B staging: dest chunks c = tid + 256*i (linear), source pre-swizzled
    size_t bsrc[2];
    int bdst[2];
    #pragma unroll
    for (int i = 0; i < 2; ++i) {
        const int c = tid + 256 * i;        // 0..511
        const int prow = c >> 3;
        const int slot = c & 7;
        const int ch = slot ^ (prow & 7);   // logical chunk
        const int col = c0 + 2 * prow + (ch >> 2);
        bdst[i] = c * 16;
        bsrc[i] = (size_t)col * (size_t)d.bstride * 2 + (size_t)((ch & 3) << 4);
    }

    f32x4 hh[4][4], xx[4][4];
    #pragma unroll
    for (int mi = 0; mi < 4; ++mi)
        #pragma unroll
        for (int ni = 0; ni < 4; ++ni) {
            hh[mi][ni] = (f32x4){0.f, 0.f, 0.f, 0.f};
            xx[mi][ni] = (f32x4){0.f, 0.f, 0.f, 0.f};
        }

    float4 areg[4];
    auto aload = [&](int kt) {
        const float* ap = aP + (size_t)kt * 32;
        #pragma unroll
        for (int i = 0; i < 4; ++i) areg[i] = *(const float4*)(ap + i * 4);
    };
    auto awrite = [&](int b) {
        #pragma unroll
        for (int j = 0; j < 2; ++j) {
            f16x8 h8, l8;
            #pragma unroll
            for (int e = 0; e < 2; ++e) {
                float4 v = areg[j * 2 + e];
                v.x *= d.ascale; v.y *= d.ascale; v.z *= d.ascale; v.w *= d.ascale;
                #pragma unroll
                for (int t2 = 0; t2 < 4; ++t2) {
                    const float f = (&v.x)[t2];
                    const f16 hv = (f16)f;
                    h8[e * 4 + t2] = hv;
                    l8[e * 4 + t2] = (f16)((f - (float)hv) * 2048.0f);
                }
            }
            *(f16x8*)((char*)&LAs[b][0][0] + awb[j]) = h8;
            *(f16x8*)((char*)&LAs[b][1][0] + awb[j]) = l8;
        }
    };
    auto bload = [&](int b, int kt) {
        const size_t kb = (size_t)kt << 6;   // 32 f16 = 64 B
        #pragma unroll
        for (int i = 0; i < 2; ++i) {
            gload16((const char*)d.BhT + bsrc[i] + kb, (char*)&LBs[b][0][0] + bdst[i]);
            gload16((const char*)d.BlT + bsrc[i] + kb, (char*)&LBs[b][1][0] + bdst[i]);
        }
    };

    aload(0); bload(0, 0); awrite(0);
    __syncthreads();

    const int NT = d.K >> 5;
    int buf = 0;
    #pragma unroll 1
    for (int kt = 0; kt < NT; ++kt) {
        const bool more = (kt + 1 < NT);
        if (more) { aload(kt + 1); bload(buf ^ 1, kt + 1); }

        {
            const int kg = lane >> 4;    // 0..3 (BK=32: one MFMA k-depth)
            f16x8 ah[4], al[4], bh[4], bl[4];
            #pragma unroll
            for (int mi = 0; mi < 4; ++mi) {
                const int rr = wm * 64 + mi * 16 + (lane & 15);
                const int prow = rr >> 1;
                const int ch = 4 * (rr & 1) + kg;
                const int byte = prow * 128 + ((ch ^ (prow & 7)) << 4);
                ah[mi] = *(const f16x8*)((const char*)&LAs[buf][0][0] + byte);
                al[mi] = *(const f16x8*)((const char*)&LAs[buf][1][0] + byte);
            }
            #pragma unroll
            for (int ni = 0; ni < 4; ++ni) {
                const int cc = wn * 64 + ni * 16 + (lane & 15);
                const int prow = cc >> 1;
                const int ch = 4 * (cc & 1) + kg;
                const int byte = prow * 128 + ((ch ^ (prow & 7)) << 4);
                bh[ni] = *(const f16x8*)((const char*)&LBs[buf][0][0] + byte);
                bl[ni] = *(const f16x8*)((const char*)&LBs[buf][1][0] + byte);
            }
            #pragma unroll
            for (int mi = 0; mi < 4; ++mi)
                #pragma unroll
                for (int ni = 0; ni < 4; ++ni) {
                    hh[mi][ni] = __builtin_amdgcn_mfma_f32_16x16x32_f16(ah[mi], bh[ni], hh[mi][ni], 0, 0, 0);
                    xx[mi][ni] = __builtin_amdgcn_mfma_f32_16x16x32_f16(ah[mi], bl[ni], xx[mi][ni], 0, 0, 0);
                    xx[mi][ni] = __builtin_amdgcn_mfma_f32_16x16x32_f16(al[mi], bh[ni], xx[mi][ni], 0, 0, 0);
                }
        }

        if (more) awrite(buf ^ 1);
        __syncthreads();
        buf ^= 1;
    }

    #pragma unroll
    for (int mi = 0; mi < 4; ++mi) {
        #pragma unroll
        for (int ni = 0; ni < 4; ++ni) {
            const int orow = wm * 64 + mi * 16 + ((lane >> 4) << 2);
            const int col  = c0 + wn * 64 + ni * 16 + (lane & 15);
            float v[4];
            #pragma unroll
            for (int r = 0; r < 4; ++r)
                v[r] = (hh[mi][ni][r] + xx[mi][ni][r] * (1.0f / 2048.0f)) * d.cscale;
            if (d.C) {
                #pragma unroll
                for (int r = 0; r < 4; ++r) {
                    const int grow = r0 + orow + r;
                    if (grow < d.M) {
                        float o = v[r];
                        if (d.amode == 2) {
                            const int arow2 = (((grow >> 5) << 6) + (grow & 31)) + 32;
                            o += d.A[(size_t)arow2 * U + col];
                        }
                        float* cp = d.C + (size_t)grow * U + col;
                        if (d.cmode == 1) *cp += o; else *cp = o;
                    }
                }
            }
            if (d.EhT && (r0 + orow) < d.M) {
                f16x4 eh, el;
                #pragma unroll
                for (int r = 0; r < 4; ++r) {
                    const float e = v[r] * d.escale;
                    eh[r] = (f16)e;
                    el[r] = (f16)((e - (float)eh[r]) * 2048.0f);
                }
                const size_t eb = (size_t)col * d.estride + d.eoff + (size_t)(r0 + orow);
                *(f16x4*)(d.EhT + eb) = eh;
                *(f16x4*)(d.ElT + eb) = el;
            }
        }
    }
}

} // namespace

extern "C" void kernel_launch(void* const* d_in, const int* in_sizes, int n_in,
                              void* d_out, int out_size, void* d_ws, size_t ws_size,
                              hipStream_t stream) {
    const float* x  = (const float*)d_in[0];   // [32, 2048, 1024]
    const float* h0 = (const float*)d_in[1];   // [32, 1024]
    const float* W  = (const float*)d_in[2];   // [1024, 1024]
    const float* R  = (const float*)d_in[3];   // [1024, 1024]
    float* out = (float*)d_out;                // [32, 1024]

    const size_t UU = (size_t)U * U;
    // ---- ws layout (~132 MB) ----
    float* Gf  = (float*)d_ws;            // 4 f32 seg slots: [s4,s5,s6,s7] (16 MB)
    float* g0  = Gf + 4 * UU;             // 32 MB
    float* g1  = g0 + (size_t)MJ * U;     // 16 MB
    float* Rp2 = g1 + (size_t)(MJ / 2) * U;
    float* Rp4 = Rp2 + UU;
    float* Qa  = Rp4 + UU;
    float* Qb  = Qa + UU;
    f16* GhT = (f16*)(Qb + UU);           // [1024][8192] (16 MB)
    f16* GlT = GhT + (size_t)U * 8192;    // 16 MB
    f16* Tb  = GlT + (size_t)U * 8192;    // 5 split pairs (20 MB)
    f16* Th[5]; f16* Tl[5];
    for (int i = 0; i < 5; ++i) { Th[i] = Tb + (size_t)i * 2 * UU; Tl[i] = Th[i] + UU; }

    auto MD = [](const float* A, const f16* Bh, const f16* Bl, float* C,
                 f16* Eh, f16* El, long eoff, long estride, long bstride,
                 int M, int K, int amode, int cmode,
                 float as_, float cs_, float es_) {
        MDesc d;
        d.A = A; d.BhT = Bh; d.BlT = Bl; d.C = C; d.EhT = Eh; d.ElT = El;
        d.bstride = bstride; d.estride = estride; d.eoff = eoff;
        d.M = M; d.K = K; d.amode = amode; d.cmode = cmode;
        d.ascale = as_; d.cscale = cs_; d.escale = es_;
        return d;
    };
    MDesc dz = MD(nullptr, nullptr, nullptr, nullptr, nullptr, nullptr,
                  0, 0, 1024, 0, 64, 0, 0, 1.f, 1.f, 1.f);
    auto MKpair = [&](MDesc a, MDesc b) {
        int y0 = (a.M + 127) >> 7, y1 = (b.M + 127) >> 7;
        int y = y0 > y1 ? y0 : y1; if (y < 1) y = 1;
        mk<<<dim3(U / 128, (unsigned)y, 2), 256, 0, stream>>>(a, b);
    };

    // 0) T-splits of R, W(->seg7); seg7 f32 copy
    tsplit<<<dim3(32, 32), 256, 0, stream>>>(R, Th[0], Tl[0], 1024, 0);
    tsplit<<<dim3(32, 32), 256, 0, stream>>>(W, GhT, GlT, 8192, 7 * 1024);
    hipMemcpyAsync(Gf + 3 * UU, W, UU * sizeof(float), hipMemcpyDeviceToDevice, stream);

    // 1) G-build + R-power chain, 3 fused launches
    MKpair(MD(R,   Th[0], Tl[0], Rp2,        Th[1], Tl[1], 0,    1024, 1024, U,     U, 0, 0, 1.f, 1.f, 1.f),
           MD(W,   Th[0], Tl[0], Gf + 2*UU,  GhT,   GlT,   6144, 8192, 1024, U,     U, 0, 0, 1.f, 1.f, 1.f));
    MKpair(MD(Rp2, Th[1], Tl[1], Rp4,        Th[2], Tl[2], 0,    1024, 1024, U,     U, 0, 0, 1.f, 1.f, 1.f),
           MD(Gf + 2*UU, Th[1], Tl[1], Gf,   GhT,   GlT,   4096, 8192, 1024, 2 * U, U, 0, 0, 1.f, 1.f, 1.f));
    MKpair(MD(Rp4, Th[2], Tl[2], Qa,         Th[3], Tl[3], 0,    1024, 1024, U,     U, 0, 0, 1.f, 1.f, 1.f),
           MD(Gf,  Th[2], Tl[2], nullptr,    GhT,   GlT,   0,    8192, 1024, 4 * U, U, 0, 0, 1.f, 1.f, 1.f));

    // 2) main GEMM: g0 = f16(x)-gather @ (Gh + 2^-11 Gl), dual-acc single pass
    main5<<<dim3(32, 8), 512, 0, stream>>>(x, GhT, GlT, g0);

    // 3) h0 inject: g0[0:32] += h0 @ R^8
    MKpair(MD(h0, Th[3], Tl[3], g0, nullptr, nullptr, 0, 0, 1024, BATCH, U, 0, 1, 1.f, 1.f, 1.f), dz);

    // 4) tree: 8 fused levels (combine || squaring). Scale schedule:
    //    sigma_l (T-split of R^(8*2^l)): {0,0,0,0,0,0,16,40}
    //    a_l (combine A prescale bits): {0,0,0,0,0,6,20,47};  cscale = 2^(a_l+sigma_l)
    const float aS[8] = {1.f, 1.f, 1.f, 1.f, 1.f,
                         1.f / 64.f, 1.f / 1048576.f, 7.105427357601002e-15f}; // 2^-47
    const float cS[8] = {1.f, 1.f, 1.f, 1.f, 1.f,
                         64.f, 68719476736.f /*2^36*/, 1.5474250491067253e26f /*2^87*/};
    float* Qcur = Qa; float* Qnxt = Qb;
    int tcur = 3, tnxt = 4;
    float* cur = g0; float* nxt = g1;
    for (int l = 0; l < 8; ++l) {
        const int M = BATCH * ((CJ / 2) >> l);    // 4096 ... 32
        MDesc dc = MD(cur, Th[tcur], Tl[tcur], (l == 7) ? out : nxt,
                      nullptr, nullptr, 0, 0, 1024, M, U, 2, 0, aS[l], cS[l], 1.f);
        MDesc dq = dz;
        if (l < 7) {
            float sq_as = 1.f, sq_cs = 1.f, sq_es = 1.f;
            float* sqC = Qnxt;
            if (l == 5) { sq_es = 1.0f / 65536.0f; }                   // emit R^512 * 2^-16
            if (l == 6) { sq_as = 1.0f / 16777216.0f; sqC = nullptr; } // R^1024 * 2^-40 emit
            dq = MD(Qcur, Th[tcur], Tl[tcur], sqC, Th[tnxt], Tl[tnxt],
                    0, 1024, 1024, U, U, 0, 0, sq_as, sq_cs, sq_es);
        }
        MKpair(dc, dq);
        float* tq = Qcur; Qcur = Qnxt; Qnxt = tq;
        int ts = tcur; tcur = tnxt; tnxt = ts;
        float* tg = cur; cur = nxt; nxt = tg;
    }
    (void)in_sizes; (void)n_in; (void)out_size; (void)ws_size;
}

// Round 10
// 951.192 us; speedup vs baseline: 1.2770x; 1.2770x over previous
//
#include <hip/hip_runtime.h>
#include <cstddef>
#include <cstdint>

// MinimalRNNCell h_T: purely linear scan.
//   g_c = sum_{i<8} x_{8c+i} @ (W R^{7-i}) -- ONE MFMA GEMM (x-gather @ stacked G^T)
//   8-level tree combine with Q_l = R^(8*2^l); h0 injected into chunk 0 pre-tree.
// R10:
//  - main reverted to R8 main4 (measured 296us): xh pre-split + ALL staging via
//    global_load_lds (async; R9 proved reg-staging A stalls the pipe).
//  - mk: transposed E-emit now bounces through LDS (free after K-loop):
//    phase1 split->swizzled col-major LDS tile, phase2 coalesced 16B global
//    stores that L2-merge into 64B lines. Was 512K scattered 8B stores = the
//    ~50us/launch tail cost. Bit-identical values.
//  - tsplit pair fused into one z=2 launch.

namespace {

constexpr int BATCH = 32;
constexpr int T = 2048;
constexpr int U = 1024;
constexpr int LJ = 8;
constexpr int CJ = T / LJ;      // 256 chunks
constexpr int MJ = CJ * BATCH;  // 8192 aggregate rows

typedef _Float16 f16;
typedef _Float16 f16x4 __attribute__((ext_vector_type(4)));
typedef _Float16 f16x8 __attribute__((ext_vector_type(8)));
typedef float f32x4 __attribute__((ext_vector_type(4)));

__device__ inline void gload16(const void* g, void* l) {
    __builtin_amdgcn_global_load_lds(
        (const __attribute__((address_space(1))) unsigned int*)g,
        (__attribute__((address_space(3))) unsigned int*)l, 16, 0, 0);
}

// ---------------- x -> f16 (hi only) ----------------
__global__ __launch_bounds__(256)
void split_x(const float* __restrict__ x, f16* __restrict__ xh, long n4)
{
    long i = (long)blockIdx.x * 256 + threadIdx.x;
    const long stride = (long)gridDim.x * 256;
    for (; i < n4; i += stride) {
        const float4 v = *(const float4*)(x + i * 4);
        f16x4 h;
        h.x = (f16)v.x; h.y = (f16)v.y; h.z = (f16)v.z; h.w = (f16)v.w;
        *(f16x4*)(xh + i * 4) = h;
    }
}

// ---------------- transpose + split fp32 [1024][1024] -> T-split (2 jobs) -------
__global__ __launch_bounds__(256)
void tsplit2(const float* __restrict__ S0, f16* __restrict__ Dh0, f16* __restrict__ Dl0,
             long dstride0, long doff0,
             const float* __restrict__ S1, f16* __restrict__ Dh1, f16* __restrict__ Dl1,
             long dstride1, long doff1)
{
    const float* S = blockIdx.z ? S1 : S0;
    f16* Dh = blockIdx.z ? Dh1 : Dh0;
    f16* Dl = blockIdx.z ? Dl1 : Dl0;
    const long dstride = blockIdx.z ? dstride1 : dstride0;
    const long doff = blockIdx.z ? doff1 : doff0;

    __shared__ float tile[32][33];
    const int t = threadIdx.x;
    const int k0 = blockIdx.x * 32;
    const int n0 = blockIdx.y * 32;
    {
        const int r = t >> 3, c4 = (t & 7) << 2;
        const float4 v = *(const float4*)(S + (size_t)(k0 + r) * U + n0 + c4);
        tile[r][c4 + 0] = v.x; tile[r][c4 + 1] = v.y;
        tile[r][c4 + 2] = v.z; tile[r][c4 + 3] = v.w;
    }
    __syncthreads();
    {
        const int c = t >> 3, r4 = (t & 7) << 2;
        float v0 = tile[r4 + 0][c], v1 = tile[r4 + 1][c],
              v2 = tile[r4 + 2][c], v3 = tile[r4 + 3][c];
        f16x4 h, lo;
        h.x = (f16)v0; lo.x = (f16)((v0 - (float)h.x) * 2048.0f);
        h.y = (f16)v1; lo.y = (f16)((v1 - (float)h.y) * 2048.0f);
        h.z = (f16)v2; lo.z = (f16)((v2 - (float)h.z) * 2048.0f);
        h.w = (f16)v3; lo.w = (f16)((v3 - (float)h.w) * 2048.0f);
        const size_t o = (size_t)(n0 + c) * dstride + doff + k0 + r4;
        *(f16x4*)(Dh + o) = h;
        *(f16x4*)(Dl + o) = lo;
    }
}

// ---------------- main GEMM: g0[8192][1024] = Xh-gather @ (Gh + 2^-11 Gl) --------
// R8 main4 verbatim: 256x128 tile, 512 thr (8 waves 4x2), BK=64, dual acc,
// dbuf LDS, all staging via global_load_lds. Measured 296 us.
__global__ __launch_bounds__(512, 2)
void main4(const f16* __restrict__ xh, const f16* __restrict__ GhT,
           const f16* __restrict__ GlT, float* __restrict__ g0)
{
    __shared__ __align__(16) f16 LA[2][16384];   // 32 KB / buf
    __shared__ __align__(16) f16 LBh[2][8192];   // 16 KB / buf
    __shared__ __align__(16) f16 LBl[2][8192];   // 16 KB / buf

    const int tid  = threadIdx.x;        // 0..511
    const int lane = tid & 63;
    const int w    = tid >> 6;           // 0..7
    const int wm   = w >> 1;             // 0..3 row quarter (64 rows)
    const int wn   = w & 1;              // 0..1 col half (64 cols)
    const int r0   = blockIdx.x * 256;   // 32 row tiles; bid%8 = rowtile%8 -> XCD
    const int c0   = blockIdx.y * 128;   // 8 col blocks

    const int ch  = tid & 7;             // 16B chunk within a 128B k-line
    const int rid = tid >> 3;            // 0..63

    size_t aof[4];
    #pragma unroll
    for (int q = 0; q < 4; ++q) {
        const int m = q * 64 + rid;      // tile row 0..255
        const int arow = r0 + m;
        const size_t xbase = ((size_t)(arow & 31) * T + (size_t)(arow >> 5) * LJ) * U;
        aof[q] = xbase * 2 + (size_t)((ch ^ (m & 7)) << 4);   // pre-swizzled src
    }
    size_t bof[2];
    #pragma unroll
    for (int q = 0; q < 2; ++q) {
        const int c = q * 64 + rid;      // tile col 0..127
        bof[q] = ((size_t)(c0 + c) << 14) + (size_t)((ch ^ (c & 7)) << 4);
    }
    const int dst = tid << 4;            // linear LDS dest (bytes)

    f32x4 hh[4][4], xx[4][4];
    #pragma unroll
    for (int mi = 0; mi < 4; ++mi)
        #pragma unroll
        for (int ni = 0; ni < 4; ++ni) {
            hh[mi][ni] = (f32x4){0.f, 0.f, 0.f, 0.f};
            xx[mi][ni] = (f32x4){0.f, 0.f, 0.f, 0.f};
        }

    auto stage = [&](int b, int kt) {
        const size_t kb = (size_t)kt << 7;   // 64 f16 = 128 B per k-step
        #pragma unroll
        for (int q = 0; q < 4; ++q)
            gload16((const char*)xh + aof[q] + kb, (char*)&LA[b][0] + q * 8192 + dst);
        #pragma unroll
        for (int q = 0; q < 2; ++q) {
            gload16((const char*)GhT + bof[q] + kb, (char*)&LBh[b][0] + q * 8192 + dst);
            gload16((const char*)GlT + bof[q] + kb, (char*)&LBl[b][0] + q * 8192 + dst);
        }
    };

    stage(0, 0);
    __syncthreads();

    int buf = 0;
    #pragma unroll 1
    for (int kt = 0; kt < 128; ++kt) {
        if (kt + 1 < 128) stage(buf ^ 1, kt + 1);   // loads fly under compute

        #pragma unroll
        for (int ks = 0; ks < 2; ++ks) {
            const int kg = ks * 4 + (lane >> 4);
            f16x8 af[4], bh[4], bl[4];
            #pragma unroll
            for (int mi = 0; mi < 4; ++mi) {
                const int rr = wm * 64 + mi * 16 + (lane & 15);
                const int byte = rr * 128 + ((kg ^ (rr & 7)) << 4);
                af[mi] = *(const f16x8*)((const char*)&LA[buf][0] + byte);
            }
            #pragma unroll
            for (int ni = 0; ni < 4; ++ni) {
                const int cc = wn * 64 + ni * 16 + (lane & 15);
                const int byte = cc * 128 + ((kg ^ (cc & 7)) << 4);
                bh[ni] = *(const f16x8*)((const char*)&LBh[buf][0] + byte);
                bl[ni] = *(const f16x8*)((const char*)&LBl[buf][0] + byte);
            }
            #pragma unroll
            for (int mi = 0; mi < 4; ++mi)
                #pragma unroll
                for (int ni = 0; ni < 4; ++ni) {
                    hh[mi][ni] = __builtin_amdgcn_mfma_f32_16x16x32_f16(af[mi], bh[ni], hh[mi][ni], 0, 0, 0);
                    xx[mi][ni] = __builtin_amdgcn_mfma_f32_16x16x32_f16(af[mi], bl[ni], xx[mi][ni], 0, 0, 0);
                }
        }
        __syncthreads();
        buf ^= 1;
    }

    // epilogue: C/D layout col=lane&15, row=(lane>>4)*4+reg (m89-verified)
    #pragma unroll
    for (int mi = 0; mi < 4; ++mi)
        #pragma unroll
        for (int ni = 0; ni < 4; ++ni) {
            const int col = c0 + wn * 64 + ni * 16 + (lane & 15);
            #pragma unroll
            for (int r = 0; r < 4; ++r) {
                const int row = r0 + wm * 64 + mi * 16 + ((lane >> 4) << 2) + r;
                g0[(size_t)row * U + col] = hh[mi][ni][r] + xx[mi][ni][r] * (1.0f / 2048.0f);
            }
        }
}

// ---------------- unified MFMA split-GEMM (chain / squarings / combines) --------
// R9 mk v2 structure (BK=32, pair-packed lines, 64KB dbuf) + R10 LDS-bounce emit.
struct MDesc {
    const float* A;
    const f16* BhT; const f16* BlT;
    float* C;
    f16* EhT; f16* ElT;
    long bstride, estride, eoff;
    int M, K;
    int amode;      // 0: row-major stride K   2: tree gather (+A2 add in epilogue)
    int cmode;      // 0: store  1: add
    float ascale, cscale, escale;
};

__global__ __launch_bounds__(256, 2)
void mk(MDesc d0, MDesc d1)
{
    MDesc d = blockIdx.z ? d1 : d0;
    const int r0 = blockIdx.y * 128;
    if (r0 >= d.M) return;
    const int c0 = blockIdx.x * 128;

    // 64 KB shared pool: staging during K-loop, E-transpose tile in epilogue.
    __shared__ __align__(16) f16 SMEM[32768];
    f16 (*LAs)[2][4096] = (f16(*)[2][4096])(&SMEM[0]);       // [2][2][4096]
    f16 (*LBs)[2][4096] = (f16(*)[2][4096])(&SMEM[16384]);   // [2][2][4096]

    const int tid = threadIdx.x;
    const int lane = tid & 63;
    const int w = tid >> 6;
    const int wm = w >> 1, wn = w & 1;

    // ---- A staging: row = tid>>1 (0..127), half = tid&1 (16 floats)
    const int arr = tid >> 1;
    const int ahalf = tid & 1;
    int arow = r0 + arr;
    if (arow >= d.M) arow = d.M - 1;
    const float* aP;
    if (d.amode == 2)
        aP = d.A + ((size_t)(((arow >> 5) << 6) + (arow & 31)) << 10);
    else
        aP = d.A + (size_t)arow * d.K;
    aP += ahalf * 16;
    int awb[2];
    #pragma unroll
    for (int j = 0; j < 2; ++j) {
        const int prow = arr >> 1;
        const int chn = 4 * (arr & 1) + 2 * ahalf + j;
        awb[j] = prow * 128 + ((chn ^ (prow & 7)) << 4);
    }

    // ---- B staging: dest chunks c = tid + 256*i (linear), source pre-swizzled
    size_t bsrc[2];
    int bdst[2];
    #pragma unroll
    for (int i = 0; i < 2; ++i) {
        const int c = tid + 256 * i;        // 0..511
        const int prow = c >> 3;
        const int slot = c & 7;
        const int chn = slot ^ (prow & 7);  // logical chunk
        const int col = c0 + 2 * prow + (chn >> 2);
        bdst[i] = c * 16;
        bsrc[i] = (size_t)col * (size_t)d.bstride * 2 + (size_t)((chn & 3) << 4);
    }

    f32x4 hh[4][4], xx[4][4];
    #pragma unroll
    for (int mi = 0; mi < 4; ++mi)
        #pragma unroll
        for (int ni = 0; ni < 4; ++ni) {
            hh[mi][ni] = (f32x4){0.f, 0.f, 0.f, 0.f};
            xx[mi][ni] = (f32x4){0.f, 0.f, 0.f, 0.f};
        }

    float4 areg[4];
    auto aload = [&](int kt) {
        const float* ap = aP + (size_t)kt * 32;
        #pragma unroll
        for (int i = 0; i < 4; ++i) areg[i] = *(const float4*)(ap + i * 4);
    };
    auto awrite = [&](int b) {
        #pragma unroll
        for (int j = 0; j < 2; ++j) {
            f16x8 h8, l8;
            #pragma unroll
            for (int e = 0; e < 2; ++e) {
                float4 v = areg[j * 2 + e];
                v.x *= d.ascale; v.y *= d.ascale; v.z *= d.ascale; v.w *= d.ascale;
                #pragma unroll
                for (int t2 = 0; t2 < 4; ++t2) {
                    const float f = (&v.x)[t2];
                    const f16 hv = (f16)f;
                    h8[e * 4 + t2] = hv;
                    l8[e * 4 + t2] = (f16)((f - (float)hv) * 2048.0f);
                }
            }
            *(f16x8*)((char*)&LAs[b][0][0] + awb[j]) = h8;
            *(f16x8*)((char*)&LAs[b][1][0] + awb[j]) = l8;
        }
    };
    auto bload = [&](int b, int kt) {
        const size_t kb = (size_t)kt << 6;   // 32 f16 = 64 B
        #pragma unroll
        for (int i = 0; i < 2; ++i) {
            gload16((const char*)d.BhT + bsrc[i] + kb, (char*)&LBs[b][0][0] + bdst[i]);
            gload16((const char*)d.BlT + bsrc[i] + kb, (char*)&LBs[b][1][0] + bdst[i]);
        }
    };

    aload(0); bload(0, 0); awrite(0);
    __syncthreads();

    const int NT = d.K >> 5;
    int buf = 0;
    #pragma unroll 1
    for (int kt = 0; kt < NT; ++kt) {
        const bool more = (kt + 1 < NT);
        if (more) { aload(kt + 1); bload(buf ^ 1, kt + 1); }

        {
            const int kg = lane >> 4;    // 0..3 (BK=32)
            f16x8 ah[4], al[4], bh[4], bl[4];
            #pragma unroll
            for (int mi = 0; mi < 4; ++mi) {
                const int rr = wm * 64 + mi * 16 + (lane & 15);
                const int prow = rr >> 1;
                const int chn = 4 * (rr & 1) + kg;
                const int byte = prow * 128 + ((chn ^ (prow & 7)) << 4);
                ah[mi] = *(const f16x8*)((const char*)&LAs[buf][0][0] + byte);
                al[mi] = *(const f16x8*)((const char*)&LAs[buf][1][0] + byte);
            }
            #pragma unroll
            for (int ni = 0; ni < 4; ++ni) {
                const int cc = wn * 64 + ni * 16 + (lane & 15);
                const int prow = cc >> 1;
                const int chn = 4 * (cc & 1) + kg;
                const int byte = prow * 128 + ((chn ^ (prow & 7)) << 4);
                bh[ni] = *(const f16x8*)((const char*)&LBs[buf][0][0] + byte);
                bl[ni] = *(const f16x8*)((const char*)&LBs[buf][1][0] + byte);
            }
            #pragma unroll
            for (int mi = 0; mi < 4; ++mi)
                #pragma unroll
                for (int ni = 0; ni < 4; ++ni) {
                    hh[mi][ni] = __builtin_amdgcn_mfma_f32_16x16x32_f16(ah[mi], bh[ni], hh[mi][ni], 0, 0, 0);
                    xx[mi][ni] = __builtin_amdgcn_mfma_f32_16x16x32_f16(ah[mi], bl[ni], xx[mi][ni], 0, 0, 0);
                    xx[mi][ni] = __builtin_amdgcn_mfma_f32_16x16x32_f16(al[mi], bh[ni], xx[mi][ni], 0, 0, 0);
                }
        }

        if (more) awrite(buf ^ 1);
        __syncthreads();
        buf ^= 1;
    }

    // ---- epilogue ----
    const bool emit = (d.EhT != nullptr);          // block-uniform
    f16* Ehs = &SMEM[0];        // [128 col][128 row] swizzled, 32 KB
    f16* Els = &SMEM[16384];

    #pragma unroll
    for (int mi = 0; mi < 4; ++mi) {
        #pragma unroll
        for (int ni = 0; ni < 4; ++ni) {
            const int orow = wm * 64 + mi * 16 + ((lane >> 4) << 2);
            const int colL = wn * 64 + ni * 16 + (lane & 15);
            const int col  = c0 + colL;
            float v[4];
            #pragma unroll
            for (int r = 0; r < 4; ++r)
                v[r] = (hh[mi][ni][r] + xx[mi][ni][r] * (1.0f / 2048.0f)) * d.cscale;
            if (d.C) {
                #pragma unroll
                for (int r = 0; r < 4; ++r) {
                    const int grow = r0 + orow + r;
                    if (grow < d.M) {
                        float o = v[r];
                        if (d.amode == 2) {
                            const int arow2 = (((grow >> 5) << 6) + (grow & 31)) + 32;
                            o += d.A[(size_t)arow2 * U + col];
                        }
                        float* cp = d.C + (size_t)grow * U + col;
                        if (d.cmode == 1) *cp += o; else *cp = o;
                    }
                }
            }
            if (emit) {
                // phase 1: split into swizzled col-major LDS tile
                f16x4 h4, l4;
                #pragma unroll
                for (int r = 0; r < 4; ++r) {
                    const float e = v[r] * d.escale;
                    h4[r] = (f16)e;
                    l4[r] = (f16)((e - (float)h4[r]) * 2048.0f);
                }
                const int blk = orow >> 3;
                const int boff = colL * 256 + ((blk ^ (colL & 15)) << 4) + (orow & 7) * 2;
                *(f16x4*)((char*)Ehs + boff) = h4;
                *(f16x4*)((char*)Els + boff) = l4;
            }
        }
    }

    if (emit) {
        __syncthreads();
        // phase 2: coalesced 16B stores (L2 merges 4 per 64B line)
        const int c  = tid & 127;
        const int b0 = (tid >> 7) * 8;     // 0 or 8
        const size_t gbase = (size_t)(c0 + c) * d.estride + d.eoff + (size_t)r0;
        #pragma unroll
        for (int i = 0; i < 8; ++i) {
            const int blk = b0 + i;
            const int off = c * 256 + ((blk ^ (c & 15)) << 4);
            *(f16x8*)(d.EhT + gbase + blk * 8) = *(const f16x8*)((char*)Ehs + off);
            *(f16x8*)(d.ElT + gbase + blk * 8) = *(const f16x8*)((char*)Els + off);
        }
    }
}

} // namespace

extern "C" void kernel_launch(void* const* d_in, const int* in_sizes, int n_in,
                              void* d_out, int out_size, void* d_ws, size_t ws_size,
                              hipStream_t stream) {
    const float* x  = (const float*)d_in[0];   // [32, 2048, 1024]
    const float* h0 = (const float*)d_in[1];   // [32, 1024]
    const float* W  = (const float*)d_in[2];   // [1024, 1024]
    const float* R  = (const float*)d_in[3];   // [1024, 1024]
    float* out = (float*)d_out;                // [32, 1024]

    const size_t UU = (size_t)U * U;
    // ---- ws layout (~260 MB) ----
    float* Gf  = (float*)d_ws;            // 4 f32 seg slots: [s4,s5,s6,s7] (16 MB)
    float* g0  = Gf + 4 * UU;             // 32 MB
    float* g1  = g0 + (size_t)MJ * U;     // 16 MB
    float* Rp2 = g1 + (size_t)(MJ / 2) * U;
    float* Rp4 = Rp2 + UU;
    float* Qa  = Rp4 + UU;
    float* Qb  = Qa + UU;
    f16* GhT = (f16*)(Qb + UU);           // [1024][8192] (16 MB)
    f16* GlT = GhT + (size_t)U * 8192;    // 16 MB
    f16* Tb  = GlT + (size_t)U * 8192;    // 5 split pairs (20 MB)
    f16* Th[5]; f16* Tl[5];
    for (int i = 0; i < 5; ++i) { Th[i] = Tb + (size_t)i * 2 * UU; Tl[i] = Th[i] + UU; }
    f16* xh = Tb + 10 * UU;               // 128 MB

    auto MD = [](const float* A, const f16* Bh, const f16* Bl, float* C,
                 f16* Eh, f16* El, long eoff, long estride, long bstride,
                 int M, int K, int amode, int cmode,
                 float as_, float cs_, float es_) {
        MDesc d;
        d.A = A; d.BhT = Bh; d.BlT = Bl; d.C = C; d.EhT = Eh; d.ElT = El;
        d.bstride = bstride; d.estride = estride; d.eoff = eoff;
        d.M = M; d.K = K; d.amode = amode; d.cmode = cmode;
        d.ascale = as_; d.cscale = cs_; d.escale = es_;
        return d;
    };
    MDesc dz = MD(nullptr, nullptr, nullptr, nullptr, nullptr, nullptr,
                  0, 0, 1024, 0, 64, 0, 0, 1.f, 1.f, 1.f);
    auto MKpair = [&](MDesc a, MDesc b) {
        int y0 = (a.M + 127) >> 7, y1 = (b.M + 127) >> 7;
        int y = y0 > y1 ? y0 : y1; if (y < 1) y = 1;
        mk<<<dim3(U / 128, (unsigned)y, 2), 256, 0, stream>>>(a, b);
    };

    // 0) x -> f16; fused T-splits of R and W(->seg7); seg7 f32 copy
    split_x<<<2048, 256, 0, stream>>>(x, xh, (long)BATCH * T * U / 4);
    tsplit2<<<dim3(32, 32, 2), 256, 0, stream>>>(R, Th[0], Tl[0], 1024, 0,
                                                 W, GhT, GlT, 8192, 7 * 1024);
    hipMemcpyAsync(Gf + 3 * UU, W, UU * sizeof(float), hipMemcpyDeviceToDevice, stream);

    // 1) G-build + R-power chain, 3 fused launches
    MKpair(MD(R,   Th[0], Tl[0], Rp2,        Th[1], Tl[1], 0,    1024, 1024, U,     U, 0, 0, 1.f, 1.f, 1.f),
           MD(W,   Th[0], Tl[0], Gf + 2*UU,  GhT,   GlT,   6144, 8192, 1024, U,     U, 0, 0, 1.f, 1.f, 1.f));
    MKpair(MD(Rp2, Th[1], Tl[1], Rp4,        Th[2], Tl[2], 0,    1024, 1024, U,     U, 0, 0, 1.f, 1.f, 1.f),
           MD(Gf + 2*UU, Th[1], Tl[1], Gf,   GhT,   GlT,   4096, 8192, 1024, 2 * U, U, 0, 0, 1.f, 1.f, 1.f));
    MKpair(MD(Rp4, Th[2], Tl[2], Qa,         Th[3], Tl[3], 0,    1024, 1024, U,     U, 0, 0, 1.f, 1.f, 1.f),
           MD(Gf,  Th[2], Tl[2], nullptr,    GhT,   GlT,   0,    8192, 1024, 4 * U, U, 0, 0, 1.f, 1.f, 1.f));

    // 2) main GEMM: g0 = xh-gather @ (Gh + 2^-11 Gl), dual-acc single pass
    main4<<<dim3(32, 8), 512, 0, stream>>>(xh, GhT, GlT, g0);

    // 3) h0 inject: g0[0:32] += h0 @ R^8
    MKpair(MD(h0, Th[3], Tl[3], g0, nullptr, nullptr, 0, 0, 1024, BATCH, U, 0, 1, 1.f, 1.f, 1.f), dz);

    // 4) tree: 8 fused levels (combine || squaring). Scale schedule:
    //    sigma_l (T-split of R^(8*2^l)): {0,0,0,0,0,0,16,40}
    //    a_l (combine A prescale bits): {0,0,0,0,0,6,20,47};  cscale = 2^(a_l+sigma_l)
    const float aS[8] = {1.f, 1.f, 1.f, 1.f, 1.f,
                         1.f / 64.f, 1.f / 1048576.f, 7.105427357601002e-15f}; // 2^-47
    const float cS[8] = {1.f, 1.f, 1.f, 1.f, 1.f,
                         64.f, 68719476736.f /*2^36*/, 1.5474250491067253e26f /*2^87*/};
    float* Qcur = Qa; float* Qnxt = Qb;
    int tcur = 3, tnxt = 4;
    float* cur = g0; float* nxt = g1;
    for (int l = 0; l < 8; ++l) {
        const int M = BATCH * ((CJ / 2) >> l);    // 4096 ... 32
        MDesc dc = MD(cur, Th[tcur], Tl[tcur], (l == 7) ? out : nxt,
                      nullptr, nullptr, 0, 0, 1024, M, U, 2, 0, aS[l], cS[l], 1.f);
        MDesc dq = dz;
        if (l < 7) {
            float sq_as = 1.f, sq_cs = 1.f, sq_es = 1.f;
            float* sqC = Qnxt;
            if (l == 5) { sq_es = 1.0f / 65536.0f; }                   // emit R^512 * 2^-16
            if (l == 6) { sq_as = 1.0f / 16777216.0f; sqC = nullptr; } // R^1024 * 2^-40 emit
            dq = MD(Qcur, Th[tcur], Tl[tcur], sqC, Th[tnxt], Tl[tnxt],
                    0, 1024, 1024, U, U, 0, 0, sq_as, sq_cs, sq_es);
        }
        MKpair(dc, dq);
        float* tq = Qcur; Qcur = Qnxt; Qnxt = tq;
        int ts = tcur; tcur = tnxt; tnxt = ts;
        float* tg = cur; cur = nxt; nxt = tg;
    }
    (void)in_sizes; (void)n_in; (void)out_size; (void)ws_size;
}

// Round 11
// 839.200 us; speedup vs baseline: 1.4474x; 1.1335x over previous
//
#include <hip/hip_runtime.h>
#include <cstddef>
#include <cstdint>

// MinimalRNNCell h_T: purely linear scan.
//   g_c = sum_{i<8} x_{8c+i} @ (W R^{7-i}) -- ONE MFMA GEMM (x-gather @ stacked G^T)
//   8-level tree combine with Q_l = R^(8*2^l); h0 injected into chunk 0 pre-tree.
// R11:
//  - mk: tile 128x64 (x-grid 16 -> 2x blocks). R10's 47us/launch was CU-coverage
//    bound: squarings were 128 blocks on 256 CUs, deep tree levels 32. Now
//    squarings = 256 blocks (full chip). 48KB LDS (3 blocks/CU capacity).
//    Same BK=32 pair-packed layout + LDS-bounce emit -> bitwise-identical output.
//  - main4 / split_x / tsplit2 unchanged (measured 296 / ~62 / ~10 us).

namespace {

constexpr int BATCH = 32;
constexpr int T = 2048;
constexpr int U = 1024;
constexpr int LJ = 8;
constexpr int CJ = T / LJ;      // 256 chunks
constexpr int MJ = CJ * BATCH;  // 8192 aggregate rows

typedef _Float16 f16;
typedef _Float16 f16x4 __attribute__((ext_vector_type(4)));
typedef _Float16 f16x8 __attribute__((ext_vector_type(8)));
typedef float f32x4 __attribute__((ext_vector_type(4)));

__device__ inline void gload16(const void* g, void* l) {
    __builtin_amdgcn_global_load_lds(
        (const __attribute__((address_space(1))) unsigned int*)g,
        (__attribute__((address_space(3))) unsigned int*)l, 16, 0, 0);
}

// ---------------- x -> f16 (hi only) ----------------
__global__ __launch_bounds__(256)
void split_x(const float* __restrict__ x, f16* __restrict__ xh, long n4)
{
    long i = (long)blockIdx.x * 256 + threadIdx.x;
    const long stride = (long)gridDim.x * 256;
    for (; i < n4; i += stride) {
        const float4 v = *(const float4*)(x + i * 4);
        f16x4 h;
        h.x = (f16)v.x; h.y = (f16)v.y; h.z = (f16)v.z; h.w = (f16)v.w;
        *(f16x4*)(xh + i * 4) = h;
    }
}

// ---------------- transpose + split fp32 [1024][1024] -> T-split (2 jobs) -------
__global__ __launch_bounds__(256)
void tsplit2(const float* __restrict__ S0, f16* __restrict__ Dh0, f16* __restrict__ Dl0,
             long dstride0, long doff0,
             const float* __restrict__ S1, f16* __restrict__ Dh1, f16* __restrict__ Dl1,
             long dstride1, long doff1)
{
    const float* S = blockIdx.z ? S1 : S0;
    f16* Dh = blockIdx.z ? Dh1 : Dh0;
    f16* Dl = blockIdx.z ? Dl1 : Dl0;
    const long dstride = blockIdx.z ? dstride1 : dstride0;
    const long doff = blockIdx.z ? doff1 : doff0;

    __shared__ float tile[32][33];
    const int t = threadIdx.x;
    const int k0 = blockIdx.x * 32;
    const int n0 = blockIdx.y * 32;
    {
        const int r = t >> 3, c4 = (t & 7) << 2;
        const float4 v = *(const float4*)(S + (size_t)(k0 + r) * U + n0 + c4);
        tile[r][c4 + 0] = v.x; tile[r][c4 + 1] = v.y;
        tile[r][c4 + 2] = v.z; tile[r][c4 + 3] = v.w;
    }
    __syncthreads();
    {
        const int c = t >> 3, r4 = (t & 7) << 2;
        float v0 = tile[r4 + 0][c], v1 = tile[r4 + 1][c],
              v2 = tile[r4 + 2][c], v3 = tile[r4 + 3][c];
        f16x4 h, lo;
        h.x = (f16)v0; lo.x = (f16)((v0 - (float)h.x) * 2048.0f);
        h.y = (f16)v1; lo.y = (f16)((v1 - (float)h.y) * 2048.0f);
        h.z = (f16)v2; lo.z = (f16)((v2 - (float)h.z) * 2048.0f);
        h.w = (f16)v3; lo.w = (f16)((v3 - (float)h.w) * 2048.0f);
        const size_t o = (size_t)(n0 + c) * dstride + doff + k0 + r4;
        *(f16x4*)(Dh + o) = h;
        *(f16x4*)(Dl + o) = lo;
    }
}

// ---------------- main GEMM: g0[8192][1024] = Xh-gather @ (Gh + 2^-11 Gl) --------
// R8 main4 verbatim (measured 296 us).
__global__ __launch_bounds__(512, 2)
void main4(const f16* __restrict__ xh, const f16* __restrict__ GhT,
           const f16* __restrict__ GlT, float* __restrict__ g0)
{
    __shared__ __align__(16) f16 LA[2][16384];
    __shared__ __align__(16) f16 LBh[2][8192];
    __shared__ __align__(16) f16 LBl[2][8192];

    const int tid  = threadIdx.x;
    const int lane = tid & 63;
    const int w    = tid >> 6;
    const int wm   = w >> 1;
    const int wn   = w & 1;
    const int r0   = blockIdx.x * 256;
    const int c0   = blockIdx.y * 128;

    const int ch  = tid & 7;
    const int rid = tid >> 3;

    size_t aof[4];
    #pragma unroll
    for (int q = 0; q < 4; ++q) {
        const int m = q * 64 + rid;
        const int arow = r0 + m;
        const size_t xbase = ((size_t)(arow & 31) * T + (size_t)(arow >> 5) * LJ) * U;
        aof[q] = xbase * 2 + (size_t)((ch ^ (m & 7)) << 4);
    }
    size_t bof[2];
    #pragma unroll
    for (int q = 0; q < 2; ++q) {
        const int c = q * 64 + rid;
        bof[q] = ((size_t)(c0 + c) << 14) + (size_t)((ch ^ (c & 7)) << 4);
    }
    const int dst = tid << 4;

    f32x4 hh[4][4], xx[4][4];
    #pragma unroll
    for (int mi = 0; mi < 4; ++mi)
        #pragma unroll
        for (int ni = 0; ni < 4; ++ni) {
            hh[mi][ni] = (f32x4){0.f, 0.f, 0.f, 0.f};
            xx[mi][ni] = (f32x4){0.f, 0.f, 0.f, 0.f};
        }

    auto stage = [&](int b, int kt) {
        const size_t kb = (size_t)kt << 7;
        #pragma unroll
        for (int q = 0; q < 4; ++q)
            gload16((const char*)xh + aof[q] + kb, (char*)&LA[b][0] + q * 8192 + dst);
        #pragma unroll
        for (int q = 0; q < 2; ++q) {
            gload16((const char*)GhT + bof[q] + kb, (char*)&LBh[b][0] + q * 8192 + dst);
            gload16((const char*)GlT + bof[q] + kb, (char*)&LBl[b][0] + q * 8192 + dst);
        }
    };

    stage(0, 0);
    __syncthreads();

    int buf = 0;
    #pragma unroll 1
    for (int kt = 0; kt < 128; ++kt) {
        if (kt + 1 < 128) stage(buf ^ 1, kt + 1);

        #pragma unroll
        for (int ks = 0; ks < 2; ++ks) {
            const int kg = ks * 4 + (lane >> 4);
            f16x8 af[4], bh[4], bl[4];
            #pragma unroll
            for (int mi = 0; mi < 4; ++mi) {
                const int rr = wm * 64 + mi * 16 + (lane & 15);
                const int byte = rr * 128 + ((kg ^ (rr & 7)) << 4);
                af[mi] = *(const f16x8*)((const char*)&LA[buf][0] + byte);
            }
            #pragma unroll
            for (int ni = 0; ni < 4; ++ni) {
                const int cc = wn * 64 + ni * 16 + (lane & 15);
                const int byte = cc * 128 + ((kg ^ (cc & 7)) << 4);
                bh[ni] = *(const f16x8*)((const char*)&LBh[buf][0] + byte);
                bl[ni] = *(const f16x8*)((const char*)&LBl[buf][0] + byte);
            }
            #pragma unroll
            for (int mi = 0; mi < 4; ++mi)
                #pragma unroll
                for (int ni = 0; ni < 4; ++ni) {
                    hh[mi][ni] = __builtin_amdgcn_mfma_f32_16x16x32_f16(af[mi], bh[ni], hh[mi][ni], 0, 0, 0);
                    xx[mi][ni] = __builtin_amdgcn_mfma_f32_16x16x32_f16(af[mi], bl[ni], xx[mi][ni], 0, 0, 0);
                }
        }
        __syncthreads();
        buf ^= 1;
    }

    #pragma unroll
    for (int mi = 0; mi < 4; ++mi)
        #pragma unroll
        for (int ni = 0; ni < 4; ++ni) {
            const int col = c0 + wn * 64 + ni * 16 + (lane & 15);
            #pragma unroll
            for (int r = 0; r < 4; ++r) {
                const int row = r0 + wm * 64 + mi * 16 + ((lane >> 4) << 2) + r;
                g0[(size_t)row * U + col] = hh[mi][ni][r] + xx[mi][ni][r] * (1.0f / 2048.0f);
            }
        }
}

// ---------------- unified MFMA split-GEMM (chain / squarings / combines) --------
// R11: 128x64 tile (x-grid 16), BK=32 pair-packed, 48KB LDS, LDS-bounce emit.
struct MDesc {
    const float* A;
    const f16* BhT; const f16* BlT;
    float* C;
    f16* EhT; f16* ElT;
    long bstride, estride, eoff;
    int M, K;
    int amode;      // 0: row-major stride K   2: tree gather (+A2 add in epilogue)
    int cmode;      // 0: store  1: add
    float ascale, cscale, escale;
};

__global__ __launch_bounds__(256, 2)
void mk(MDesc d0, MDesc d1)
{
    MDesc d = blockIdx.z ? d1 : d0;
    const int r0 = blockIdx.y * 128;
    if (r0 >= d.M) return;
    const int c0 = blockIdx.x * 64;

    // 48 KB pool: staging in K-loop; E-transpose tile (32 KB) in epilogue.
    __shared__ __align__(16) f16 SMEM[24576];
    f16 (*LAs)[2][4096] = (f16(*)[2][4096])(&SMEM[0]);       // 2 bufs x h/l x 8KB
    f16 (*LBs)[2][2048] = (f16(*)[2][2048])(&SMEM[16384]);   // 2 bufs x h/l x 4KB

    const int tid = threadIdx.x;
    const int lane = tid & 63;
    const int w = tid >> 6;
    const int wm = w >> 1, wn = w & 1;   // wave = 64 rows x 32 cols

    // ---- A staging: row = tid>>1 (0..127), half = tid&1 (16 floats)
    const int arr = tid >> 1;
    const int ahalf = tid & 1;
    int arow = r0 + arr;
    if (arow >= d.M) arow = d.M - 1;
    const float* aP;
    if (d.amode == 2)
        aP = d.A + ((size_t)(((arow >> 5) << 6) + (arow & 31)) << 10);
    else
        aP = d.A + (size_t)arow * d.K;
    aP += ahalf * 16;
    int awb[2];
    #pragma unroll
    for (int j = 0; j < 2; ++j) {
        const int prow = arr >> 1;
        const int chn = 4 * (arr & 1) + 2 * ahalf + j;
        awb[j] = prow * 128 + ((chn ^ (prow & 7)) << 4);
    }

    // ---- B staging: 1 chunk per thread (64 cols pair-packed into 32 lines)
    const int bprow = tid >> 3;                // 0..31
    const int bslot = tid & 7;
    const int bchn  = bslot ^ (bprow & 7);     // logical chunk
    const size_t bsrc = (size_t)(c0 + 2 * bprow + (bchn >> 2)) * (size_t)d.bstride * 2
                      + (size_t)((bchn & 3) << 4);
    const int bdst = tid * 16;

    f32x4 hh[4][2], xx[4][2];
    #pragma unroll
    for (int mi = 0; mi < 4; ++mi)
        #pragma unroll
        for (int ni = 0; ni < 2; ++ni) {
            hh[mi][ni] = (f32x4){0.f, 0.f, 0.f, 0.f};
            xx[mi][ni] = (f32x4){0.f, 0.f, 0.f, 0.f};
        }

    float4 areg[4];
    auto aload = [&](int kt) {
        const float* ap = aP + (size_t)kt * 32;
        #pragma unroll
        for (int i = 0; i < 4; ++i) areg[i] = *(const float4*)(ap + i * 4);
    };
    auto awrite = [&](int b) {
        #pragma unroll
        for (int j = 0; j < 2; ++j) {
            f16x8 h8, l8;
            #pragma unroll
            for (int e = 0; e < 2; ++e) {
                float4 v = areg[j * 2 + e];
                v.x *= d.ascale; v.y *= d.ascale; v.z *= d.ascale; v.w *= d.ascale;
                #pragma unroll
                for (int t2 = 0; t2 < 4; ++t2) {
                    const float f = (&v.x)[t2];
                    const f16 hv = (f16)f;
                    h8[e * 4 + t2] = hv;
                    l8[e * 4 + t2] = (f16)((f - (float)hv) * 2048.0f);
                }
            }
            *(f16x8*)((char*)&LAs[b][0][0] + awb[j]) = h8;
            *(f16x8*)((char*)&LAs[b][1][0] + awb[j]) = l8;
        }
    };
    auto bload = [&](int b, int kt) {
        const size_t kb = (size_t)kt << 6;   // 32 f16 = 64 B
        gload16((const char*)d.BhT + bsrc + kb, (char*)&LBs[b][0][0] + bdst);
        gload16((const char*)d.BlT + bsrc + kb, (char*)&LBs[b][1][0] + bdst);
    };

    aload(0); bload(0, 0); awrite(0);
    __syncthreads();

    const int NT = d.K >> 5;
    int buf = 0;
    #pragma unroll 1
    for (int kt = 0; kt < NT; ++kt) {
        const bool more = (kt + 1 < NT);
        if (more) { aload(kt + 1); bload(buf ^ 1, kt + 1); }

        {
            const int kg = lane >> 4;    // 0..3 (BK=32)
            f16x8 ah[4], al[4], bh[2], bl[2];
            #pragma unroll
            for (int mi = 0; mi < 4; ++mi) {
                const int rr = wm * 64 + mi * 16 + (lane & 15);
                const int prow = rr >> 1;
                const int chn = 4 * (rr & 1) + kg;
                const int byte = prow * 128 + ((chn ^ (prow & 7)) << 4);
                ah[mi] = *(const f16x8*)((const char*)&LAs[buf][0][0] + byte);
                al[mi] = *(const f16x8*)((const char*)&LAs[buf][1][0] + byte);
            }
            #pragma unroll
            for (int ni = 0; ni < 2; ++ni) {
                const int cc = wn * 32 + ni * 16 + (lane & 15);
                const int prow = cc >> 1;
                const int chn = 4 * (cc & 1) + kg;
                const int byte = prow * 128 + ((chn ^ (prow & 7)) << 4);
                bh[ni] = *(const f16x8*)((const char*)&LBs[buf][0][0] + byte);
                bl[ni] = *(const f16x8*)((const char*)&LBs[buf][1][0] + byte);
            }
            #pragma unroll
            for (int mi = 0; mi < 4; ++mi)
                #pragma unroll
                for (int ni = 0; ni < 2; ++ni) {
                    hh[mi][ni] = __builtin_amdgcn_mfma_f32_16x16x32_f16(ah[mi], bh[ni], hh[mi][ni], 0, 0, 0);
                    xx[mi][ni] = __builtin_amdgcn_mfma_f32_16x16x32_f16(ah[mi], bl[ni], xx[mi][ni], 0, 0, 0);
                    xx[mi][ni] = __builtin_amdgcn_mfma_f32_16x16x32_f16(al[mi], bh[ni], xx[mi][ni], 0, 0, 0);
                }
        }

        if (more) awrite(buf ^ 1);
        __syncthreads();
        buf ^= 1;
    }

    // ---- epilogue ----
    const bool emit = (d.EhT != nullptr);          // block-uniform
    f16* Ehs = &SMEM[0];       // [64 col][128 row] swizzled, 16 KB
    f16* Els = &SMEM[8192];

    #pragma unroll
    for (int mi = 0; mi < 4; ++mi) {
        #pragma unroll
        for (int ni = 0; ni < 2; ++ni) {
            const int orow = wm * 64 + mi * 16 + ((lane >> 4) << 2);
            const int colL = wn * 32 + ni * 16 + (lane & 15);
            const int col  = c0 + colL;
            float v[4];
            #pragma unroll
            for (int r = 0; r < 4; ++r)
                v[r] = (hh[mi][ni][r] + xx[mi][ni][r] * (1.0f / 2048.0f)) * d.cscale;
            if (d.C) {
                #pragma unroll
                for (int r = 0; r < 4; ++r) {
                    const int grow = r0 + orow + r;
                    if (grow < d.M) {
                        float o = v[r];
                        if (d.amode == 2) {
                            const int arow2 = (((grow >> 5) << 6) + (grow & 31)) + 32;
                            o += d.A[(size_t)arow2 * U + col];
                        }
                        float* cp = d.C + (size_t)grow * U + col;
                        if (d.cmode == 1) *cp += o; else *cp = o;
                    }
                }
            }
            if (emit) {
                f16x4 h4, l4;
                #pragma unroll
                for (int r = 0; r < 4; ++r) {
                    const float e = v[r] * d.escale;
                    h4[r] = (f16)e;
                    l4[r] = (f16)((e - (float)h4[r]) * 2048.0f);
                }
                const int blk = orow >> 3;
                const int boff = colL * 256 + ((blk ^ (colL & 15)) << 4) + (orow & 7) * 2;
                *(f16x4*)((char*)Ehs + boff) = h4;
                *(f16x4*)((char*)Els + boff) = l4;
            }
        }
    }

    if (emit) {
        __syncthreads();
        // coalesced 16B stores (L2 merges into 64B lines)
        const int c  = tid & 63;
        const int b0 = (tid >> 6) * 4;     // 0,4,8,12
        const size_t gbase = (size_t)(c0 + c) * d.estride + d.eoff + (size_t)r0;
        #pragma unroll
        for (int i = 0; i < 4; ++i) {
            const int blk = b0 + i;
            const int off = c * 256 + ((blk ^ (c & 15)) << 4);
            *(f16x8*)(d.EhT + gbase + blk * 8) = *(const f16x8*)((char*)Ehs + off);
            *(f16x8*)(d.ElT + gbase + blk * 8) = *(const f16x8*)((char*)Els + off);
        }
    }
}

} // namespace

extern "C" void kernel_launch(void* const* d_in, const int* in_sizes, int n_in,
                              void* d_out, int out_size, void* d_ws, size_t ws_size,
                              hipStream_t stream) {
    const float* x  = (const float*)d_in[0];   // [32, 2048, 1024]
    const float* h0 = (const float*)d_in[1];   // [32, 1024]
    const float* W  = (const float*)d_in[2];   // [1024, 1024]
    const float* R  = (const float*)d_in[3];   // [1024, 1024]
    float* out = (float*)d_out;                // [32, 1024]

    const size_t UU = (size_t)U * U;
    // ---- ws layout (~260 MB) ----
    float* Gf  = (float*)d_ws;            // 4 f32 seg slots: [s4,s5,s6,s7] (16 MB)
    float* g0  = Gf + 4 * UU;             // 32 MB
    float* g1  = g0 + (size_t)MJ * U;     // 16 MB
    float* Rp2 = g1 + (size_t)(MJ / 2) * U;
    float* Rp4 = Rp2 + UU;
    float* Qa  = Rp4 + UU;
    float* Qb  = Qa + UU;
    f16* GhT = (f16*)(Qb + UU);           // [1024][8192] (16 MB)
    f16* GlT = GhT + (size_t)U * 8192;    // 16 MB
    f16* Tb  = GlT + (size_t)U * 8192;    // 5 split pairs (20 MB)
    f16* Th[5]; f16* Tl[5];
    for (int i = 0; i < 5; ++i) { Th[i] = Tb + (size_t)i * 2 * UU; Tl[i] = Th[i] + UU; }
    f16* xh = Tb + 10 * UU;               // 128 MB

    auto MD = [](const float* A, const f16* Bh, const f16* Bl, float* C,
                 f16* Eh, f16* El, long eoff, long estride, long bstride,
                 int M, int K, int amode, int cmode,
                 float as_, float cs_, float es_) {
        MDesc d;
        d.A = A; d.BhT = Bh; d.BlT = Bl; d.C = C; d.EhT = Eh; d.ElT = El;
        d.bstride = bstride; d.estride = estride; d.eoff = eoff;
        d.M = M; d.K = K; d.amode = amode; d.cmode = cmode;
        d.ascale = as_; d.cscale = cs_; d.escale = es_;
        return d;
    };
    MDesc dz = MD(nullptr, nullptr, nullptr, nullptr, nullptr, nullptr,
                  0, 0, 1024, 0, 64, 0, 0, 1.f, 1.f, 1.f);
    auto MKpair = [&](MDesc a, MDesc b) {
        int y0 = (a.M + 127) >> 7, y1 = (b.M + 127) >> 7;
        int y = y0 > y1 ? y0 : y1; if (y < 1) y = 1;
        mk<<<dim3(U / 64, (unsigned)y, 2), 256, 0, stream>>>(a, b);
    };

    // 0) x -> f16; fused T-splits of R and W(->seg7); seg7 f32 copy
    split_x<<<2048, 256, 0, stream>>>(x, xh, (long)BATCH * T * U / 4);
    tsplit2<<<dim3(32, 32, 2), 256, 0, stream>>>(R, Th[0], Tl[0], 1024, 0,
                                                 W, GhT, GlT, 8192, 7 * 1024);
    hipMemcpyAsync(Gf + 3 * UU, W, UU * sizeof(float), hipMemcpyDeviceToDevice, stream);

    // 1) G-build + R-power chain, 3 fused launches
    MKpair(MD(R,   Th[0], Tl[0], Rp2,        Th[1], Tl[1], 0,    1024, 1024, U,     U, 0, 0, 1.f, 1.f, 1.f),
           MD(W,   Th[0], Tl[0], Gf + 2*UU,  GhT,   GlT,   6144, 8192, 1024, U,     U, 0, 0, 1.f, 1.f, 1.f));
    MKpair(MD(Rp2, Th[1], Tl[1], Rp4,        Th[2], Tl[2], 0,    1024, 1024, U,     U, 0, 0, 1.f, 1.f, 1.f),
           MD(Gf + 2*UU, Th[1], Tl[1], Gf,   GhT,   GlT,   4096, 8192, 1024, 2 * U, U, 0, 0, 1.f, 1.f, 1.f));
    MKpair(MD(Rp4, Th[2], Tl[2], Qa,         Th[3], Tl[3], 0,    1024, 1024, U,     U, 0, 0, 1.f, 1.f, 1.f),
           MD(Gf,  Th[2], Tl[2], nullptr,    GhT,   GlT,   0,    8192, 1024, 4 * U, U, 0, 0, 1.f, 1.f, 1.f));

    // 2) main GEMM: g0 = xh-gather @ (Gh + 2^-11 Gl), dual-acc single pass
    main4<<<dim3(32, 8), 512, 0, stream>>>(xh, GhT, GlT, g0);

    // 3) h0 inject: g0[0:32] += h0 @ R^8
    MKpair(MD(h0, Th[3], Tl[3], g0, nullptr, nullptr, 0, 0, 1024, BATCH, U, 0, 1, 1.f, 1.f, 1.f), dz);

    // 4) tree: 8 fused levels (combine || squaring). Scale schedule:
    //    sigma_l (T-split of R^(8*2^l)): {0,0,0,0,0,0,16,40}
    //    a_l (combine A prescale bits): {0,0,0,0,0,6,20,47};  cscale = 2^(a_l+sigma_l)
    const float aS[8] = {1.f, 1.f, 1.f, 1.f, 1.f,
                         1.f / 64.f, 1.f / 1048576.f, 7.105427357601002e-15f}; // 2^-47
    const float cS[8] = {1.f, 1.f, 1.f, 1.f, 1.f,
                         64.f, 68719476736.f /*2^36*/, 1.5474250491067253e26f /*2^87*/};
    float* Qcur = Qa; float* Qnxt = Qb;
    int tcur = 3, tnxt = 4;
    float* cur = g0; float* nxt = g1;
    for (int l = 0; l < 8; ++l) {
        const int M = BATCH * ((CJ / 2) >> l);    // 4096 ... 32
        MDesc dc = MD(cur, Th[tcur], Tl[tcur], (l == 7) ? out : nxt,
                      nullptr, nullptr, 0, 0, 1024, M, U, 2, 0, aS[l], cS[l], 1.f);
        MDesc dq = dz;
        if (l < 7) {
            float sq_as = 1.f, sq_cs = 1.f, sq_es = 1.f;
            float* sqC = Qnxt;
            if (l == 5) { sq_es = 1.0f / 65536.0f; }                   // emit R^512 * 2^-16
            if (l == 6) { sq_as = 1.0f / 16777216.0f; sqC = nullptr; } // R^1024 * 2^-40 emit
            dq = MD(Qcur, Th[tcur], Tl[tcur], sqC, Th[tnxt], Tl[tnxt],
                    0, 1024, 1024, U, U, 0, 0, sq_as, sq_cs, sq_es);
        }
        MKpair(dc, dq);
        float* tq = Qcur; Qcur = Qnxt; Qnxt = tq;
        int ts = tcur; tcur = tnxt; tnxt = ts;
        float* tg = cur; cur = nxt; nxt = tg;
    }
    (void)in_sizes; (void)n_in; (void)out_size; (void)ws_size;
}

// Round 13
// 802.359 us; speedup vs baseline: 1.5138x; 1.0459x over previous
//
#include <hip/hip_runtime.h>
#include <cstddef>
#include <cstdint>

// MinimalRNNCell h_T: purely linear scan.
//   g_c = sum_{i<8} x_{8c+i} @ (W R^{7-i}) -- ONE MFMA GEMM (x-gather @ stacked G^T)
//   8-level tree combine with Q_l = R^(8*2^l); h0 injected into chunk 0 pre-tree.
// R13 (= R12 with the const-pointer rotation compile fix): the whole tail goes
// pure-async. Every GEMM producer row-emits the h/l f16 split of its output; mk2
// stages BOTH operands via global_load_lds (no fp32 reg-staging anywhere in the
// K-loop -- the R9/R11 A-latency stall is gone). fp32 C kept only for the tree's
// odd-chunk epilogue-add + final out. Same products, same order, same power-of-2
// scales => bitwise-identical result (absmax must stay 1.622593e32).

namespace {

constexpr int BATCH = 32;
constexpr int T = 2048;
constexpr int U = 1024;
constexpr int LJ = 8;
constexpr int CJ = T / LJ;      // 256 chunks
constexpr int MJ = CJ * BATCH;  // 8192 aggregate rows

typedef _Float16 f16;
typedef _Float16 f16x4 __attribute__((ext_vector_type(4)));
typedef _Float16 f16x8 __attribute__((ext_vector_type(8)));
typedef float f32x4 __attribute__((ext_vector_type(4)));

__device__ inline void gload16(const void* g, void* l) {
    __builtin_amdgcn_global_load_lds(
        (const __attribute__((address_space(1))) unsigned int*)g,
        (__attribute__((address_space(3))) unsigned int*)l, 16, 0, 0);
}

// ---------------- x -> f16 (hi only) ----------------
__global__ __launch_bounds__(256)
void split_x(const float* __restrict__ x, f16* __restrict__ xh, long n4)
{
    long i = (long)blockIdx.x * 256 + threadIdx.x;
    const long stride = (long)gridDim.x * 256;
    for (; i < n4; i += stride) {
        const float4 v = *(const float4*)(x + i * 4);
        f16x4 h;
        h.x = (f16)v.x; h.y = (f16)v.y; h.z = (f16)v.z; h.w = (f16)v.w;
        *(f16x4*)(xh + i * 4) = h;
    }
}

// ---------------- prep: T-split + row-split of R and W; row-split h0 ------------
__global__ __launch_bounds__(256)
void prep(const float* __restrict__ R, const float* __restrict__ W,
          const float* __restrict__ h0,
          f16* __restrict__ TTRh, f16* __restrict__ TTRl,
          f16* __restrict__ Rrh, f16* __restrict__ Rrl,
          f16* __restrict__ GhT, f16* __restrict__ GlT,
          f16* __restrict__ Wrh, f16* __restrict__ Wrl,
          f16* __restrict__ h0rh, f16* __restrict__ h0rl)
{
    const int z = blockIdx.z;
    const float* S = z ? W : R;
    f16* Dh = z ? GhT : TTRh;
    f16* Dl = z ? GlT : TTRl;
    const long dstride = z ? 8192 : 1024;
    const long doff = z ? 7168 : 0;
    f16* Rh_ = z ? Wrh : Rrh;
    f16* Rl_ = z ? Wrl : Rrl;

    __shared__ float tile[32][33];
    const int t = threadIdx.x;
    const int k0 = blockIdx.x * 32;
    const int n0 = blockIdx.y * 32;
    {
        const int r = t >> 3, c4 = (t & 7) << 2;
        const float4 v = *(const float4*)(S + (size_t)(k0 + r) * U + n0 + c4);
        tile[r][c4 + 0] = v.x; tile[r][c4 + 1] = v.y;
        tile[r][c4 + 2] = v.z; tile[r][c4 + 3] = v.w;
        f16x4 h, lo;
        h.x = (f16)v.x; lo.x = (f16)((v.x - (float)h.x) * 2048.0f);
        h.y = (f16)v.y; lo.y = (f16)((v.y - (float)h.y) * 2048.0f);
        h.z = (f16)v.z; lo.z = (f16)((v.z - (float)h.z) * 2048.0f);
        h.w = (f16)v.w; lo.w = (f16)((v.w - (float)h.w) * 2048.0f);
        const size_t ro = (size_t)(k0 + r) * U + n0 + c4;
        *(f16x4*)(Rh_ + ro) = h;
        *(f16x4*)(Rl_ + ro) = lo;
    }
    __syncthreads();
    {
        const int c = t >> 3, r4 = (t & 7) << 2;
        float v0 = tile[r4 + 0][c], v1 = tile[r4 + 1][c],
              v2 = tile[r4 + 2][c], v3 = tile[r4 + 3][c];
        f16x4 h, lo;
        h.x = (f16)v0; lo.x = (f16)((v0 - (float)h.x) * 2048.0f);
        h.y = (f16)v1; lo.y = (f16)((v1 - (float)h.y) * 2048.0f);
        h.z = (f16)v2; lo.z = (f16)((v2 - (float)h.z) * 2048.0f);
        h.w = (f16)v3; lo.w = (f16)((v3 - (float)h.w) * 2048.0f);
        const size_t o = (size_t)(n0 + c) * dstride + doff + k0 + r4;
        *(f16x4*)(Dh + o) = h;
        *(f16x4*)(Dl + o) = lo;
    }
    if (z == 1 && blockIdx.x == 0) {
        const int r = t >> 3, c4 = (t & 7) << 2;
        const float4 v = *(const float4*)(h0 + (size_t)r * U + n0 + c4);
        f16x4 h, lo;
        h.x = (f16)v.x; lo.x = (f16)((v.x - (float)h.x) * 2048.0f);
        h.y = (f16)v.y; lo.y = (f16)((v.y - (float)h.y) * 2048.0f);
        h.z = (f16)v.z; lo.z = (f16)((v.z - (float)h.z) * 2048.0f);
        h.w = (f16)v.w; lo.w = (f16)((v.w - (float)h.w) * 2048.0f);
        const size_t ro = (size_t)r * U + n0 + c4;
        *(f16x4*)(h0rh + ro) = h;
        *(f16x4*)(h0rl + ro) = lo;
    }
}

// ---------------- main GEMM (R8 main4 + g0 row-emit) ----------------------------
__global__ __launch_bounds__(512, 2)
void main4(const f16* __restrict__ xh, const f16* __restrict__ GhT,
           const f16* __restrict__ GlT, float* __restrict__ g0,
           f16* __restrict__ g0rh, f16* __restrict__ g0rl)
{
    __shared__ __align__(16) f16 LA[2][16384];
    __shared__ __align__(16) f16 LBh[2][8192];
    __shared__ __align__(16) f16 LBl[2][8192];

    const int tid  = threadIdx.x;
    const int lane = tid & 63;
    const int w    = tid >> 6;
    const int wm   = w >> 1;
    const int wn   = w & 1;
    const int r0   = blockIdx.x * 256;
    const int c0   = blockIdx.y * 128;

    const int ch  = tid & 7;
    const int rid = tid >> 3;

    size_t aof[4];
    #pragma unroll
    for (int q = 0; q < 4; ++q) {
        const int m = q * 64 + rid;
        const int arow = r0 + m;
        const size_t xbase = ((size_t)(arow & 31) * T + (size_t)(arow >> 5) * LJ) * U;
        aof[q] = xbase * 2 + (size_t)((ch ^ (m & 7)) << 4);
    }
    size_t bof[2];
    #pragma unroll
    for (int q = 0; q < 2; ++q) {
        const int c = q * 64 + rid;
        bof[q] = ((size_t)(c0 + c) << 14) + (size_t)((ch ^ (c & 7)) << 4);
    }
    const int dst = tid << 4;

    f32x4 hh[4][4], xx[4][4];
    #pragma unroll
    for (int mi = 0; mi < 4; ++mi)
        #pragma unroll
        for (int ni = 0; ni < 4; ++ni) {
            hh[mi][ni] = (f32x4){0.f, 0.f, 0.f, 0.f};
            xx[mi][ni] = (f32x4){0.f, 0.f, 0.f, 0.f};
        }

    auto stage = [&](int b, int kt) {
        const size_t kb = (size_t)kt << 7;
        #pragma unroll
        for (int q = 0; q < 4; ++q)
            gload16((const char*)xh + aof[q] + kb, (char*)&LA[b][0] + q * 8192 + dst);
        #pragma unroll
        for (int q = 0; q < 2; ++q) {
            gload16((const char*)GhT + bof[q] + kb, (char*)&LBh[b][0] + q * 8192 + dst);
            gload16((const char*)GlT + bof[q] + kb, (char*)&LBl[b][0] + q * 8192 + dst);
        }
    };

    stage(0, 0);
    __syncthreads();

    int buf = 0;
    #pragma unroll 1
    for (int kt = 0; kt < 128; ++kt) {
        if (kt + 1 < 128) stage(buf ^ 1, kt + 1);

        #pragma unroll
        for (int ks = 0; ks < 2; ++ks) {
            const int kg = ks * 4 + (lane >> 4);
            f16x8 af[4], bh[4], bl[4];
            #pragma unroll
            for (int mi = 0; mi < 4; ++mi) {
                const int rr = wm * 64 + mi * 16 + (lane & 15);
                const int byte = rr * 128 + ((kg ^ (rr & 7)) << 4);
                af[mi] = *(const f16x8*)((const char*)&LA[buf][0] + byte);
            }
            #pragma unroll
            for (int ni = 0; ni < 4; ++ni) {
                const int cc = wn * 64 + ni * 16 + (lane & 15);
                const int byte = cc * 128 + ((kg ^ (cc & 7)) << 4);
                bh[ni] = *(const f16x8*)((const char*)&LBh[buf][0] + byte);
                bl[ni] = *(const f16x8*)((const char*)&LBl[buf][0] + byte);
            }
            #pragma unroll
            for (int mi = 0; mi < 4; ++mi)
                #pragma unroll
                for (int ni = 0; ni < 4; ++ni) {
                    hh[mi][ni] = __builtin_amdgcn_mfma_f32_16x16x32_f16(af[mi], bh[ni], hh[mi][ni], 0, 0, 0);
                    xx[mi][ni] = __builtin_amdgcn_mfma_f32_16x16x32_f16(af[mi], bl[ni], xx[mi][ni], 0, 0, 0);
                }
        }
        __syncthreads();
        buf ^= 1;
    }

    #pragma unroll
    for (int mi = 0; mi < 4; ++mi)
        #pragma unroll
        for (int ni = 0; ni < 4; ++ni) {
            const int col = c0 + wn * 64 + ni * 16 + (lane & 15);
            #pragma unroll
            for (int r = 0; r < 4; ++r) {
                const int row = r0 + wm * 64 + mi * 16 + ((lane >> 4) << 2) + r;
                const float val = hh[mi][ni][r] + xx[mi][ni][r] * (1.0f / 2048.0f);
                const size_t o = (size_t)row * U + col;
                g0[o] = val;
                const f16 hv = (f16)val;
                g0rh[o] = hv;
                g0rl[o] = (f16)((val - (float)hv) * 2048.0f);
            }
        }
}

// ---------------- mk2: all-async split-GEMM (K=1024 fixed) ----------------------
// 128x64 tile, BK=32, pair-packed 128B lines, A AND B staged via global_load_lds.
struct MDesc {
    const f16* Ah; const f16* Al;     // row-major [M][1024] pair
    const f16* BhT; const f16* BlT;   // col-major [1024][1024] pair
    const float* Aadd;                // fp32 for amode2 epilogue add
    float* C;                         // fp32 out (or null)
    f16* EhT; f16* ElT;               // transposed emit (or null)
    f16* Rh; f16* Rl;                 // row-split emit (or null)
    long estride, eoff;
    int M;
    int amode;      // 0 linear, 2 tree gather
    int cmode;      // 0 store, 1 add (RMW)
    float cscale, escale, fescale;
};

__global__ __launch_bounds__(256, 2)
void mk2(MDesc d0, MDesc d1)
{
    MDesc d = blockIdx.z ? d1 : d0;
    const int r0 = blockIdx.y * 128;
    if (r0 >= d.M) return;
    const int c0 = blockIdx.x * 64;

    __shared__ __align__(16) f16 SMEM[24576];                // 48 KB
    f16 (*LAs)[2][4096] = (f16(*)[2][4096])(&SMEM[0]);       // [buf][h/l] 8KB
    f16 (*LBs)[2][2048] = (f16(*)[2][2048])(&SMEM[16384]);   // [buf][h/l] 4KB

    const int tid = threadIdx.x;
    const int lane = tid & 63;
    const int w = tid >> 6;
    const int wm = w >> 1, wn = w & 1;

    // A staging: 2 chunks/thread per h/l; pair-packed lines, pre-swizzled source
    size_t asrc[2]; int adst[2];
    #pragma unroll
    for (int i = 0; i < 2; ++i) {
        const int c = tid + 256 * i;
        const int prow = c >> 3;
        const int chn = (c & 7) ^ (prow & 7);
        const int row = 2 * prow + (chn >> 2);
        int gr = r0 + row;
        if (gr >= d.M) gr = d.M - 1;
        const int ar = (d.amode == 2) ? (((gr >> 5) << 6) + (gr & 31)) : gr;
        asrc[i] = (size_t)ar * 2048 + (size_t)((chn & 3) << 4);
        adst[i] = c * 16;
    }
    // B staging: 1 chunk/thread per h/l
    const int bprow = tid >> 3;
    const int bchn = (tid & 7) ^ (bprow & 7);
    const size_t bsrc = (size_t)(c0 + 2 * bprow + (bchn >> 2)) * 2048
                      + (size_t)((bchn & 3) << 4);
    const int bdst = tid * 16;

    f32x4 hh[4][2], xx[4][2];
    #pragma unroll
    for (int mi = 0; mi < 4; ++mi)
        #pragma unroll
        for (int ni = 0; ni < 2; ++ni) {
            hh[mi][ni] = (f32x4){0.f, 0.f, 0.f, 0.f};
            xx[mi][ni] = (f32x4){0.f, 0.f, 0.f, 0.f};
        }

    auto stage = [&](int b, int kt) {
        const size_t kb = (size_t)kt << 6;   // 32 f16 = 64 B
        #pragma unroll
        for (int i = 0; i < 2; ++i) {
            gload16((const char*)d.Ah + asrc[i] + kb, (char*)&LAs[b][0][0] + adst[i]);
            gload16((const char*)d.Al + asrc[i] + kb, (char*)&LAs[b][1][0] + adst[i]);
        }
        gload16((const char*)d.BhT + bsrc + kb, (char*)&LBs[b][0][0] + bdst);
        gload16((const char*)d.BlT + bsrc + kb, (char*)&LBs[b][1][0] + bdst);
    };

    stage(0, 0);
    __syncthreads();

    int buf = 0;
    #pragma unroll 1
    for (int kt = 0; kt < 32; ++kt) {
        if (kt + 1 < 32) stage(buf ^ 1, kt + 1);

        {
            const int kg = lane >> 4;
            f16x8 ah[4], al[4], bh[2], bl[2];
            #pragma unroll
            for (int mi = 0; mi < 4; ++mi) {
                const int rr = wm * 64 + mi * 16 + (lane & 15);
                const int prow = rr >> 1;
                const int chn = 4 * (rr & 1) + kg;
                const int byte = prow * 128 + ((chn ^ (prow & 7)) << 4);
                ah[mi] = *(const f16x8*)((const char*)&LAs[buf][0][0] + byte);
                al[mi] = *(const f16x8*)((const char*)&LAs[buf][1][0] + byte);
            }
            #pragma unroll
            for (int ni = 0; ni < 2; ++ni) {
                const int cc = wn * 32 + ni * 16 + (lane & 15);
                const int prow = cc >> 1;
                const int chn = 4 * (cc & 1) + kg;
                const int byte = prow * 128 + ((chn ^ (prow & 7)) << 4);
                bh[ni] = *(const f16x8*)((const char*)&LBs[buf][0][0] + byte);
                bl[ni] = *(const f16x8*)((const char*)&LBs[buf][1][0] + byte);
            }
            #pragma unroll
            for (int mi = 0; mi < 4; ++mi)
                #pragma unroll
                for (int ni = 0; ni < 2; ++ni) {
                    hh[mi][ni] = __builtin_amdgcn_mfma_f32_16x16x32_f16(ah[mi], bh[ni], hh[mi][ni], 0, 0, 0);
                    xx[mi][ni] = __builtin_amdgcn_mfma_f32_16x16x32_f16(ah[mi], bl[ni], xx[mi][ni], 0, 0, 0);
                    xx[mi][ni] = __builtin_amdgcn_mfma_f32_16x16x32_f16(al[mi], bh[ni], xx[mi][ni], 0, 0, 0);
                }
        }
        __syncthreads();
        buf ^= 1;
    }

    // ---- epilogue ----
    const bool temit = (d.EhT != nullptr);
    f16* Ehs = &SMEM[0];       // [64 col][128 row] swizzled, 16 KB each
    f16* Els = &SMEM[8192];

    #pragma unroll
    for (int mi = 0; mi < 4; ++mi) {
        #pragma unroll
        for (int ni = 0; ni < 2; ++ni) {
            const int orow = wm * 64 + mi * 16 + ((lane >> 4) << 2);
            const int colL = wn * 32 + ni * 16 + (lane & 15);
            const int col  = c0 + colL;
            float o[4];
            #pragma unroll
            for (int r = 0; r < 4; ++r) {
                o[r] = (hh[mi][ni][r] + xx[mi][ni][r] * (1.0f / 2048.0f)) * d.cscale;
                const int grow = r0 + orow + r;
                if (grow < d.M) {
                    if (d.amode == 2) {
                        const int arow2 = (((grow >> 5) << 6) + (grow & 31)) + 32;
                        o[r] += d.Aadd[(size_t)arow2 * U + col];
                    }
                    if (d.C) {
                        float* cp = d.C + (size_t)grow * U + col;
                        if (d.cmode == 1) o[r] += *cp;
                        *cp = o[r];
                    }
                    if (d.Rh) {
                        const float e = o[r] * d.fescale;
                        const f16 hv = (f16)e;
                        d.Rh[(size_t)grow * U + col] = hv;
                        d.Rl[(size_t)grow * U + col] = (f16)((e - (float)hv) * 2048.0f);
                    }
                }
            }
            if (temit && (r0 + orow) < d.M) {
                f16x4 h4, l4;
                #pragma unroll
                for (int r = 0; r < 4; ++r) {
                    const float e = o[r] * d.escale;
                    h4[r] = (f16)e;
                    l4[r] = (f16)((e - (float)h4[r]) * 2048.0f);
                }
                const int blk = orow >> 3;
                const int boff = colL * 256 + ((blk ^ (colL & 15)) << 4) + (orow & 7) * 2;
                *(f16x4*)((char*)Ehs + boff) = h4;
                *(f16x4*)((char*)Els + boff) = l4;
            }
        }
    }

    if (temit) {
        __syncthreads();
        const int c  = tid & 63;
        const int b0 = (tid >> 6) * 4;
        const size_t gbase = (size_t)(c0 + c) * d.estride + d.eoff + (size_t)r0;
        #pragma unroll
        for (int i = 0; i < 4; ++i) {
            const int blk = b0 + i;
            const int off = c * 256 + ((blk ^ (c & 15)) << 4);
            *(f16x8*)(d.EhT + gbase + blk * 8) = *(const f16x8*)((char*)Ehs + off);
            *(f16x8*)(d.ElT + gbase + blk * 8) = *(const f16x8*)((char*)Els + off);
        }
    }
}

} // namespace

extern "C" void kernel_launch(void* const* d_in, const int* in_sizes, int n_in,
                              void* d_out, int out_size, void* d_ws, size_t ws_size,
                              hipStream_t stream) {
    const float* x  = (const float*)d_in[0];
    const float* h0 = (const float*)d_in[1];
    const float* W  = (const float*)d_in[2];
    const float* R  = (const float*)d_in[3];
    float* out = (float*)d_out;

    const size_t M1 = (size_t)1024 * 1024;
    // ---- fp32 region (64 MB) ----
    float* g0 = (float*)d_ws;            // 8*M1
    float* gA = g0 + 8 * M1;             // 4*M1
    float* gB = gA + 4 * M1;             // 4*M1
    // ---- f16 region (~300 MB) ----
    f16* fp = (f16*)(gB + 4 * M1);
    auto take = [&](size_t n) { f16* r = fp; fp += n; return r; };
    f16* xh   = take(64 * M1);
    f16* GhT  = take(8 * M1);
    f16* GlT  = take(8 * M1);
    f16* Tqh[8]; f16* Tql[8];
    for (int l = 0; l < 8; ++l) { Tqh[l] = take(M1); Tql[l] = take(M1); }
    f16* Qrh[7]; f16* Qrl[7];
    for (int l = 0; l < 7; ++l) { Qrh[l] = take(M1); Qrl[l] = take(M1); }
    f16* Gfrh = take(4 * M1); f16* Gfrl = take(4 * M1);
    f16* h0rh = take(32 * 1024); f16* h0rl = take(32 * 1024);
    f16* g0rh = take(8 * M1); f16* g0rl = take(8 * M1);
    f16* gArh = take(4 * M1); f16* gArl = take(4 * M1);
    f16* gBrh = take(4 * M1); f16* gBrl = take(4 * M1);
    // aliases (time-disjoint):
    f16* TTRh = Tqh[3]; f16* TTRl = Tql[3];   // T(R): used L1 only; Tq3 written tree l=1
    f16* TT1h = Tqh[1]; f16* TT1l = Tql[1];   // T(R^2): used L2; Tq1 written at inject
    f16* TT2h = Tqh[2]; f16* TT2l = Tql[2];   // T(R^4): used L3; Tq2 written tree l=0
    f16* Rrh  = Qrh[3]; f16* Rrl  = Qrl[3];   // row(R): used L1; Qr3 written tree l=1
    f16* R2rh = Qrh[1]; f16* R2rl = Qrl[1];   // row(R^2): used L2; Qr1 written at inject
    f16* R4rh = Qrh[2]; f16* R4rl = Qrl[2];   // row(R^4): used L3; Qr2 written tree l=0

    auto MD2 = [](const f16* Ah, const f16* Al, const f16* Bh, const f16* Bl,
                  const float* Aadd, float* C, f16* Eh, f16* El, long eoff, long estride,
                  f16* Rh, f16* Rl, int M, int amode, int cmode,
                  float cs, float es, float fs) {
        MDesc d;
        d.Ah = Ah; d.Al = Al; d.BhT = Bh; d.BlT = Bl; d.Aadd = Aadd; d.C = C;
        d.EhT = Eh; d.ElT = El; d.Rh = Rh; d.Rl = Rl;
        d.estride = estride; d.eoff = eoff; d.M = M; d.amode = amode; d.cmode = cmode;
        d.cscale = cs; d.escale = es; d.fescale = fs;
        return d;
    };
    MDesc dz = MD2(nullptr, nullptr, nullptr, nullptr, nullptr, nullptr,
                   nullptr, nullptr, 0, 1024, nullptr, nullptr, 0, 0, 0, 1.f, 1.f, 1.f);
    auto PAIR = [&](MDesc a, MDesc b) {
        int y0 = (a.M + 127) >> 7, y1 = (b.M + 127) >> 7;
        int y = y0 > y1 ? y0 : y1; if (y < 1) y = 1;
        mk2<<<dim3(16, (unsigned)y, 2), 256, 0, stream>>>(a, b);
    };

    // 0) conversions
    split_x<<<2048, 256, 0, stream>>>(x, xh, (long)BATCH * T * U / 4);
    prep<<<dim3(32, 32, 2), 256, 0, stream>>>(R, W, h0, TTRh, TTRl, Rrh, Rrl,
                                              GhT, GlT,
                                              Gfrh + 3 * M1, Gfrl + 3 * M1,
                                              h0rh, h0rl);

    // 1) G-build + R-power chain, 3 fused launches
    PAIR(MD2(Rrh, Rrl, TTRh, TTRl, nullptr, nullptr, TT1h, TT1l, 0, 1024,
             R2rh, R2rl, U, 0, 0, 1.f, 1.f, 1.f),                               // R^2
         MD2(Gfrh + 3 * M1, Gfrl + 3 * M1, TTRh, TTRl, nullptr, nullptr,
             GhT, GlT, 6144, 8192, Gfrh + 2 * M1, Gfrl + 2 * M1, U, 0, 0, 1.f, 1.f, 1.f)); // WR -> seg6
    PAIR(MD2(R2rh, R2rl, TT1h, TT1l, nullptr, nullptr, TT2h, TT2l, 0, 1024,
             R4rh, R4rl, U, 0, 0, 1.f, 1.f, 1.f),                               // R^4
         MD2(Gfrh + 2 * M1, Gfrl + 2 * M1, TT1h, TT1l, nullptr, nullptr,
             GhT, GlT, 4096, 8192, Gfrh, Gfrl, 2 * U, 0, 0, 1.f, 1.f, 1.f));    // segs 4,5
    PAIR(MD2(R4rh, R4rl, TT2h, TT2l, nullptr, nullptr, Tqh[0], Tql[0], 0, 1024,
             Qrh[0], Qrl[0], U, 0, 0, 1.f, 1.f, 1.f),                           // R^8
         MD2(Gfrh, Gfrl, TT2h, TT2l, nullptr, nullptr,
             GhT, GlT, 0, 8192, nullptr, nullptr, 4 * U, 0, 0, 1.f, 1.f, 1.f)); // segs 0..3

    // 2) main GEMM (emits g0 row-split)
    main4<<<dim3(32, 8), 512, 0, stream>>>(xh, GhT, GlT, g0, g0rh, g0rl);

    // 3) inject (g0[0:32] += h0 @ R^8, RMW + re-emit) || squaring0 (Q1 = Q0^2)
    PAIR(MD2(h0rh, h0rl, Tqh[0], Tql[0], nullptr, g0, nullptr, nullptr, 0, 1024,
             g0rh, g0rl, BATCH, 0, 1, 1.f, 1.f, 1.f),
         MD2(Qrh[0], Qrl[0], Tqh[0], Tql[0], nullptr, nullptr, Tqh[1], Tql[1], 0, 1024,
             Qrh[1], Qrl[1], U, 0, 0, 1.f, 1.f, 1.f));

    // 4) tree: 8 levels; combine l || squaring l+1
    const float aS[9] = {1.f, 1.f, 1.f, 1.f, 1.f,
                         0.015625f, 9.5367431640625e-07f, 7.105427357601002e-15f, 0.f};
    const float cS[8] = {1.f, 1.f, 1.f, 1.f, 1.f,
                         64.f, 68719476736.f, 1.5474250491067253e26f};
    float* gcur = g0; f16* gcrh = g0rh; f16* gcrl = g0rl;
    float* gnxt = gA; f16* gnrh = gArh; f16* gnrl = gArl;
    float* gprv = gB; f16* gprh = gBrh; f16* gprl = gBrl;
    for (int l = 0; l < 8; ++l) {
        const int M = BATCH * ((CJ / 2) >> l);    // 4096 ... 32
        MDesc dc = MD2(gcrh, gcrl, Tqh[l], Tql[l], gcur, (l == 7) ? out : gnxt,
                       nullptr, nullptr, 0, 1024,
                       (l < 7) ? gnrh : nullptr, (l < 7) ? gnrl : nullptr,
                       M, 2, 0, cS[l], 1.f, aS[l + 1]);
        MDesc dq = dz;
        if (l < 6) {
            const int s = l + 1;                   // squaring index
            const float fe = (s == 5) ? 5.960464477539063e-08f : 1.f;   // 2^-24
            const float te = (s == 5) ? 1.52587890625e-05f : 1.f;       // 2^-16
            f16* reh = (s + 1 <= 6) ? Qrh[s + 1] : nullptr;
            f16* rel = (s + 1 <= 6) ? Qrl[s + 1] : nullptr;
            dq = MD2(Qrh[s], Qrl[s], Tqh[s], Tql[s], nullptr, nullptr,
                     Tqh[s + 1], Tql[s + 1], 0, 1024, reh, rel, U, 0, 0, 1.f, te, fe);
        }
        PAIR(dc, dq);
        // rotate (all mutable f16* -- R12's compile error was const here)
        float* tf = gprv; gprv = gcur; gcur = gnxt; gnxt = tf;
        f16* th = gprh; f16* tl = gprl;
        gprh = gcrh; gprl = gcrl;
        gcrh = gnrh; gcrl = gnrl;
        gnrh = th;   gnrl = tl;
    }
    (void)in_sizes; (void)n_in; (void)out_size; (void)ws_size;
}